// Round 11
// baseline (746.339 us; speedup 1.0000x reference)
//
#include <hip/hip_runtime.h>
#include <hip/hip_bf16.h>
#include <math.h>

// Problem constants (from reference): B=16, S=1024, D=64, H=4, DFF=256, L=2
#define BB 16
#define SS 1024
#define DD 64
#define HH 4
#define DEPTH 16
#define DFF 256
#define NROWS (BB*SS)        // 16384 token rows
#define EPSV 1e-6f

typedef float f32x2 __attribute__((ext_vector_type(2)));

// Packed fp32 FMA: c.lo += a.lo*b.lo ; c.hi += a.hi*b.hi  (one VOP3P instr).
// R10 LESSON: pk_fma halves instruction count; ~4-cyc op (same FLOP rate),
// so it relieves issue pressure, not raw FLOP time. -7% on attn.
__device__ __forceinline__ void pk_fma(f32x2& c, f32x2 a, f32x2 b) {
  asm("v_pk_fma_f32 %0, %1, %2, %0" : "+v"(c) : "v"(a), "v"(b));
}
__device__ __forceinline__ f32x2 lo2(float4 v) { f32x2 r; r.x = v.x; r.y = v.y; return r; }
__device__ __forceinline__ f32x2 hi2(float4 v) { f32x2 r; r.x = v.z; r.y = v.w; return r; }

// Broadcast lane kk of x to all lanes via v_readlane (no LDS traffic).
// R5/R7 LESSON (x2): readlane-with-one-live-scalar is the ONLY validated
// broadcast when ~64+ weight VGPRs are live. R8: no LDS-dependent branch at
// loop head. R9: manual LDS software-pipelining is neutral.
__device__ __forceinline__ float bcast(float x, int kk) {
  return __int_as_float(__builtin_amdgcn_readlane(__float_as_int(x), kk));
}

// ---------------------------------------------------------------------------
// Kernel 1: build x (B,S,D) and keep (B,S).
// ---------------------------------------------------------------------------
__global__ __launch_bounds__(256) void build_x_kernel(
    const float* __restrict__ inputs, const float* __restrict__ emb,
    float* __restrict__ x, float* __restrict__ keep) {
  int gid = blockIdx.x * 256 + threadIdx.x;   // over NROWS*64 elements
  int row = gid >> 6;
  int d = gid & 63;
  int s = row & (SS - 1);
  float vin = inputs[row];
  bool nan = __builtin_isnan(vin);
  float kp = nan ? 0.0f : 1.0f;
  if (d == 0) keep[row] = kp;
  float val;
  if (d < 63) {
    const float scale = 7.93725393319377f * 8.0f;  // sqrt(63)*sqrt(64)
    val = emb[s * 63 + d] * scale;
  } else {
    val = nan ? 0.0f : vin;
  }
  x[row * 64 + d] = val * kp;
}

// ---------------------------------------------------------------------------
// Kernel 2: QKV projection, weights-in-VGPR + readlane broadcast (R4 form —
// best measured). q,k,v layout (B,H,S,DEPTH).
// ---------------------------------------------------------------------------
__global__ __launch_bounds__(64, 2) void qkv_kernel(
    const float* __restrict__ xin,
    const float* __restrict__ wq, const float* __restrict__ wqb,
    const float* __restrict__ wk, const float* __restrict__ wkb,
    const float* __restrict__ wv, const float* __restrict__ wvb,
    float* __restrict__ q, float* __restrict__ k, float* __restrict__ v) {
  int lane = threadIdx.x;
  float wqc[64], wkc[64], wvc[64];
#pragma unroll
  for (int kk = 0; kk < 64; ++kk) {
    wqc[kk] = wq[kk * 64 + lane];
    wkc[kk] = wk[kk * 64 + lane];
    wvc[kk] = wv[kk * 64 + lane];
  }
  float bq = wqb[lane], bk = wkb[lane], bv = wvb[lane];
  int h = lane >> 4, dep = lane & 15;
  int row0 = blockIdx.x * 8;
  for (int r = row0; r < row0 + 8; ++r) {
    float xr = xin[r * 64 + lane];
    float qa0 = 0.f, qa1 = 0.f, ka0 = 0.f, ka1 = 0.f, va0 = 0.f, va1 = 0.f;
#pragma unroll
    for (int kk = 0; kk < 64; kk += 2) {
      float x0 = bcast(xr, kk);
      float x1 = bcast(xr, kk + 1);
      qa0 = fmaf(x0, wqc[kk], qa0); qa1 = fmaf(x1, wqc[kk + 1], qa1);
      ka0 = fmaf(x0, wkc[kk], ka0); ka1 = fmaf(x1, wkc[kk + 1], ka1);
      va0 = fmaf(x0, wvc[kk], va0); va1 = fmaf(x1, wvc[kk + 1], va1);
    }
    int b = r >> 10, s = r & (SS - 1);
    size_t o = (size_t)(((b * HH + h) * SS + s)) * DEPTH + dep;
    q[o] = qa0 + qa1 + bq;
    k[o] = ka0 + ka1 + bk;
    v[o] = va0 + va1 + bv;
  }
}

// ---------------------------------------------------------------------------
// Kernel 3: split-K attention partials, 2 queries/thread, K/V chunk in LDS,
// packed-fp32 math. Templated on KCH (keys per chunk): KCH=64 -> 16 chunks,
// 2048 blocks, 8 blocks/CU, 32 waves/CU (stall hiding); KCH=128 -> R10's
// proven 8-chunk config (workspace fallback). q pre-scaled by 0.25 (exact
// pow2). No max-subtraction softmax (exact for this data); partials combine
// by plain addition -> deterministic split-K.
// ---------------------------------------------------------------------------
template <int KCH>
__global__ __launch_bounds__(256, 8) void attn_partial_kernel(
    const float* __restrict__ q, const float* __restrict__ k,
    const float* __restrict__ v, const float* __restrict__ keep,
    float* __restrict__ pA, float* __restrict__ pL) {
  __shared__ __align__(16) float klds[KCH * DEPTH];
  __shared__ __align__(16) float vlds[KCH * DEPTH];
  __shared__ float kplds[KCH];
  int tid = threadIdx.x;
  int p = blockIdx.x * 256 + tid;                // pair id [0, 32768)
  int c = blockIdx.y;                            // key chunk
  int bh = p >> 9;                               // 512 pairs per (b,h)
  int s0 = p & 511;
  int b = bh >> 2;

  const float4* kbase = (const float4*)(k + ((size_t)bh * SS + c * KCH) * DEPTH);
  const float4* vbase = (const float4*)(v + ((size_t)bh * SS + c * KCH) * DEPTH);
#pragma unroll
  for (int i = 0; i < KCH * 4 / 256; ++i) {
    ((float4*)klds)[tid + i * 256] = kbase[tid + i * 256];
    ((float4*)vlds)[tid + i * 256] = vbase[tid + i * 256];
  }
  if (tid < KCH) kplds[tid] = keep[b * SS + c * KCH + tid];
  __syncthreads();

  size_t rowA = (size_t)bh * SS + s0;
  size_t rowB = rowA + 512;
  const float4* qa4 = (const float4*)(q + rowA * DEPTH);
  const float4* qb4 = (const float4*)(q + rowB * DEPTH);
  f32x2 qA[8], qB[8];
#pragma unroll
  for (int i = 0; i < 4; ++i) {
    float4 ta = qa4[i], tb = qb4[i];
    qA[2 * i].x     = ta.x * 0.25f; qA[2 * i].y     = ta.y * 0.25f;
    qA[2 * i + 1].x = ta.z * 0.25f; qA[2 * i + 1].y = ta.w * 0.25f;
    qB[2 * i].x     = tb.x * 0.25f; qB[2 * i].y     = tb.y * 0.25f;
    qB[2 * i + 1].x = tb.z * 0.25f; qB[2 * i + 1].y = tb.w * 0.25f;
  }
  f32x2 z2; z2.x = 0.f; z2.y = 0.f;
  f32x2 aA[8], aB[8];
#pragma unroll
  for (int i = 0; i < 8; ++i) { aA[i] = z2; aB[i] = z2; }
  float lA = 0.0f, lB = 0.0f;
  const float4* kl4 = (const float4*)klds;
  const float4* vl4 = (const float4*)vlds;
  for (int j = 0; j < KCH; ++j) {
    float4 k0 = kl4[j * 4 + 0], k1 = kl4[j * 4 + 1];
    float4 k2 = kl4[j * 4 + 2], k3 = kl4[j * 4 + 3];
    float4 v0 = vl4[j * 4 + 0], v1 = vl4[j * 4 + 1];
    float4 v2 = vl4[j * 4 + 2], v3 = vl4[j * 4 + 3];
    float kpj = kplds[j];
    f32x2 kk0 = lo2(k0), kk1 = hi2(k0), kk2 = lo2(k1), kk3 = hi2(k1);
    f32x2 kk4 = lo2(k2), kk5 = hi2(k2), kk6 = lo2(k3), kk7 = hi2(k3);
    f32x2 dA = z2, dB = z2;
    pk_fma(dA, qA[0], kk0); pk_fma(dB, qB[0], kk0);
    pk_fma(dA, qA[1], kk1); pk_fma(dB, qB[1], kk1);
    pk_fma(dA, qA[2], kk2); pk_fma(dB, qB[2], kk2);
    pk_fma(dA, qA[3], kk3); pk_fma(dB, qB[3], kk3);
    pk_fma(dA, qA[4], kk4); pk_fma(dB, qB[4], kk4);
    pk_fma(dA, qA[5], kk5); pk_fma(dB, qB[5], kk5);
    pk_fma(dA, qA[6], kk6); pk_fma(dB, qB[6], kk6);
    pk_fma(dA, qA[7], kk7); pk_fma(dB, qB[7], kk7);
    float pa = __expf(dA.x + dA.y) * kpj;
    float pb = __expf(dB.x + dB.y) * kpj;
    lA += pa; lB += pb;
    f32x2 pa2, pb2;
    pa2.x = pa; pa2.y = pa; pb2.x = pb; pb2.y = pb;
    f32x2 vv0 = lo2(v0), vv1 = hi2(v0), vv2 = lo2(v1), vv3 = hi2(v1);
    f32x2 vv4 = lo2(v2), vv5 = hi2(v2), vv6 = lo2(v3), vv7 = hi2(v3);
    pk_fma(aA[0], pa2, vv0); pk_fma(aB[0], pb2, vv0);
    pk_fma(aA[1], pa2, vv1); pk_fma(aB[1], pb2, vv1);
    pk_fma(aA[2], pa2, vv2); pk_fma(aB[2], pb2, vv2);
    pk_fma(aA[3], pa2, vv3); pk_fma(aB[3], pb2, vv3);
    pk_fma(aA[4], pa2, vv4); pk_fma(aB[4], pb2, vv4);
    pk_fma(aA[5], pa2, vv5); pk_fma(aB[5], pb2, vv5);
    pk_fma(aA[6], pa2, vv6); pk_fma(aB[6], pb2, vv6);
    pk_fma(aA[7], pa2, vv7); pk_fma(aB[7], pb2, vv7);
  }
  size_t oA = ((size_t)c << 16) + rowA;
  size_t oB = ((size_t)c << 16) + rowB;
  pL[oA] = lA; pL[oB] = lB;
  float4* o4a = (float4*)(pA + oA * 16);
  o4a[0] = make_float4(aA[0].x, aA[0].y, aA[1].x, aA[1].y);
  o4a[1] = make_float4(aA[2].x, aA[2].y, aA[3].x, aA[3].y);
  o4a[2] = make_float4(aA[4].x, aA[4].y, aA[5].x, aA[5].y);
  o4a[3] = make_float4(aA[6].x, aA[6].y, aA[7].x, aA[7].y);
  float4* o4b = (float4*)(pA + oB * 16);
  o4b[0] = make_float4(aB[0].x, aB[0].y, aB[1].x, aB[1].y);
  o4b[1] = make_float4(aB[2].x, aB[2].y, aB[3].x, aB[3].y);
  o4b[2] = make_float4(aB[4].x, aB[4].y, aB[5].x, aB[5].y);
  o4b[3] = make_float4(aB[6].x, aB[6].y, aB[7].x, aB[7].y);
}

// ---------------------------------------------------------------------------
// Kernel 4: out1 = LayerNorm(x + ctx@wo) * keep, fused split-K combine
// (nk = runtime chunk count). R4 proven form: wo column in VGPRs, readlane.
// ---------------------------------------------------------------------------
__global__ __launch_bounds__(256) void wo_ln1_kernel(
    const float* __restrict__ pA, const float* __restrict__ pL,
    const float* __restrict__ xin,
    const float* __restrict__ wo, const float* __restrict__ g,
    const float* __restrict__ bta, const float* __restrict__ keep,
    float* __restrict__ out1, int nk) {
  int tid = threadIdx.x;
  int lane = tid & 63;
  float woc[64];
#pragma unroll
  for (int kk = 0; kk < 64; ++kk) woc[kk] = wo[kk * 64 + lane];
  float gg = g[lane], bb = bta[lane];
  int wave = tid >> 6;
  int row0 = blockIdx.x * 16 + wave * 4;
  for (int r = row0; r < row0 + 4; ++r) {
    int b = r >> 10, s = r & (SS - 1);
    int h = lane >> 4, dep = lane & 15;
    size_t rowi = ((size_t)(b * HH + h) << 10) + s;
    float num = 0.0f, den = 0.0f;
    for (int c = 0; c < nk; ++c) {
      num += pA[(((size_t)c << 16) + rowi) * 16 + dep];
      den += pL[((size_t)c << 16) + rowi];
    }
    float cr = num * keep[r] / den;   // keep==0 -> exact 0 (den>0 always)
    float a0 = 0.f, a1 = 0.f;
#pragma unroll
    for (int kk = 0; kk < 64; kk += 2) {
      a0 = fmaf(bcast(cr, kk), woc[kk], a0);
      a1 = fmaf(bcast(cr, kk + 1), woc[kk + 1], a1);
    }
    float t = a0 + a1 + xin[r * 64 + lane];
    float sum = t;
#pragma unroll
    for (int off = 32; off; off >>= 1) sum += __shfl_xor(sum, off, 64);
    float mean = sum * (1.0f / 64.0f);
    float dv = t - mean;
    float sq = dv * dv;
#pragma unroll
    for (int off = 32; off; off >>= 1) sq += __shfl_xor(sq, off, 64);
    float var = sq * (1.0f / 64.0f);
    float o = dv * rsqrtf(var + EPSV) * gg + bb;
    out1[r * 64 + lane] = o * keep[r];
  }
}

// ---------------------------------------------------------------------------
// Kernel 5: fused FFN: x = LayerNorm(out1 + relu(out1@W1)@W2) * keep.
// R4 proven form: readlane broadcasts in both phases.
// ---------------------------------------------------------------------------
__global__ __launch_bounds__(256) void ffn_fused_kernel(
    const float* __restrict__ out1, const float* __restrict__ w1,
    const float* __restrict__ w2, const float* __restrict__ g,
    const float* __restrict__ bta, const float* __restrict__ keep,
    float* __restrict__ xout) {
  __shared__ float part[4][4][64];   // [row-in-group][wave][lane]
  int tid = threadIdx.x, wave = tid >> 6, lane = tid & 63;
  float w1c[64], w2c[64];
#pragma unroll
  for (int kk = 0; kk < 64; ++kk)
    w1c[kk] = w1[kk * 256 + wave * 64 + lane];     // W1[kk][wave*64+lane]
#pragma unroll
  for (int j = 0; j < 64; ++j)
    w2c[j] = w2[(wave * 64 + j) * 64 + lane];      // W2[wave*64+j][lane]
  float gg = g[lane], bb = bta[lane];
  int row0 = blockIdx.x * 16;
  for (int grp = 0; grp < 4; ++grp) {
    int rbase = row0 + grp * 4;
    float xr0 = out1[(rbase + 0) * 64 + lane];
    float xr1 = out1[(rbase + 1) * 64 + lane];
    float xr2 = out1[(rbase + 2) * 64 + lane];
    float xr3 = out1[(rbase + 3) * 64 + lane];
    float xrs[4] = {xr0, xr1, xr2, xr3};
#pragma unroll
    for (int r = 0; r < 4; ++r) {
      float h0 = 0.f, h1 = 0.f;
#pragma unroll
      for (int kk = 0; kk < 64; kk += 2) {
        h0 = fmaf(bcast(xrs[r], kk), w1c[kk], h0);
        h1 = fmaf(bcast(xrs[r], kk + 1), w1c[kk + 1], h1);
      }
      float hv = fmaxf(h0 + h1, 0.0f);
      float y0 = 0.f, y1 = 0.f;
#pragma unroll
      for (int j = 0; j < 64; j += 2) {
        y0 = fmaf(bcast(hv, j), w2c[j], y0);
        y1 = fmaf(bcast(hv, j + 1), w2c[j + 1], y1);
      }
      part[r][wave][lane] = y0 + y1;
    }
    __syncthreads();
    // wave w finishes row rbase+w (compile-time select, no scratch)
    float xres = (wave == 0) ? xr0 : (wave == 1) ? xr1 : (wave == 2) ? xr2 : xr3;
    float t = part[wave][0][lane] + part[wave][1][lane] +
              part[wave][2][lane] + part[wave][3][lane] + xres;
    float sum = t;
#pragma unroll
    for (int off = 32; off; off >>= 1) sum += __shfl_xor(sum, off, 64);
    float mean = sum * (1.0f / 64.0f);
    float dv = t - mean;
    float sq = dv * dv;
#pragma unroll
    for (int off = 32; off; off >>= 1) sq += __shfl_xor(sq, off, 64);
    float var = sq * (1.0f / 64.0f);
    float o = dv * rsqrtf(var + EPSV) * gg + bb;
    xout[(rbase + wave) * 64 + lane] = o * keep[rbase + wave];
    __syncthreads();   // before next group overwrites part
  }
}

// ---------------------------------------------------------------------------
// Kernel 6: init output: out[b] = out_bias[0]
// ---------------------------------------------------------------------------
__global__ void init_out_kernel(const float* __restrict__ out_bias,
                                float* __restrict__ out) {
  if (threadIdx.x < BB) out[threadIdx.x] = out_bias[0];
}

// ---------------------------------------------------------------------------
// Kernel 7: classifier, weights-in-VGPR + readlane (R4 proven form).
// ---------------------------------------------------------------------------
__global__ __launch_bounds__(256, 3) void classifier_kernel(
    const float* __restrict__ x,
    const float* __restrict__ w1, const float* __restrict__ b1,
    const float* __restrict__ w2, const float* __restrict__ b2,
    const float* __restrict__ w3, const float* __restrict__ b3,
    float* __restrict__ out) {
  int tid = threadIdx.x;
  int lane = tid & 63, wave = tid >> 6;
  float w1c[64], w2c[64];
#pragma unroll
  for (int kk = 0; kk < 64; ++kk) {
    w1c[kk] = w1[kk * 64 + lane];
    w2c[kk] = w2[kk * 64 + lane];
  }
  float w3d = w3[lane];
  float bb1 = b1[lane], bb2 = b2[lane], b3v = b3[0];
  int row0 = blockIdx.x * 32 + wave * 8;
  float wavesum = 0.0f;
  for (int r = row0; r < row0 + 8; ++r) {
    float xr = x[r * 64 + lane];
    float h1a = 0.f, h1b = 0.f;
#pragma unroll
    for (int kk = 0; kk < 64; kk += 2) {
      h1a = fmaf(bcast(xr, kk), w1c[kk], h1a);
      h1b = fmaf(bcast(xr, kk + 1), w1c[kk + 1], h1b);
    }
    float h1 = fmaxf(h1a + h1b + bb1, 0.0f);
    float h2a = 0.f, h2b = 0.f;
#pragma unroll
    for (int kk = 0; kk < 64; kk += 2) {
      h2a = fmaf(bcast(h1, kk), w2c[kk], h2a);
      h2b = fmaf(bcast(h1, kk + 1), w2c[kk + 1], h2b);
    }
    float h2 = fmaxf(h2a + h2b + bb2, 0.0f);
    float p = h2 * w3d;
#pragma unroll
    for (int off = 32; off; off >>= 1) p += __shfl_xor(p, off, 64);
    wavesum += p + b3v;
  }
  if (lane == 0) {
    int b = row0 >> 10;
    atomicAdd(&out[b], wavesum);
  }
}

// ---------------------------------------------------------------------------
extern "C" void kernel_launch(void* const* d_in, const int* in_sizes, int n_in,
                              void* d_out, int out_size, void* d_ws, size_t ws_size,
                              hipStream_t stream) {
  const float* inputs = (const float*)d_in[0];
  const float* emb    = (const float*)d_in[1];
  const float* wq     = (const float*)d_in[2];
  const float* wqb    = (const float*)d_in[3];
  const float* wk     = (const float*)d_in[4];
  const float* wkb    = (const float*)d_in[5];
  const float* wv     = (const float*)d_in[6];
  const float* wvb    = (const float*)d_in[7];
  const float* wo     = (const float*)d_in[8];
  const float* fw1    = (const float*)d_in[9];
  const float* fw2    = (const float*)d_in[10];
  const float* l1g    = (const float*)d_in[11];
  const float* l1b    = (const float*)d_in[12];
  const float* l2g    = (const float*)d_in[13];
  const float* l2b    = (const float*)d_in[14];
  const float* cw1    = (const float*)d_in[15];
  const float* cb1    = (const float*)d_in[16];
  const float* cw2    = (const float*)d_in[17];
  const float* cb2    = (const float*)d_in[18];
  const float* cw3    = (const float*)d_in[19];
  const float* cb3    = (const float*)d_in[20];
  const float* obias  = (const float*)d_in[21];
  float* out = (float*)d_out;

  // Choose split-K factor by available workspace: NK=16 needs ~92 MB,
  // NK=8 (R10 fallback) ~56 MB. Selection is ws_size-driven (fixed per
  // harness), so every call takes the same path (graph-capture safe).
  size_t base_floats = (size_t)NROWS * 64 * 5 + NROWS;   // x,q,k,v,out1,keep
  size_t need16 = (base_floats + (size_t)16 * 65536 * 17) * 4;
  int nk = (ws_size >= need16) ? 16 : 8;

  float* ws   = (float*)d_ws;
  float* x    = ws;                           // NROWS*64
  float* keep = x    + (size_t)NROWS * 64;    // NROWS
  float* q    = keep + NROWS;                 // NROWS*64  (B,H,S,DEPTH)
  float* k    = q    + (size_t)NROWS * 64;
  float* v    = k    + (size_t)NROWS * 64;
  float* out1 = v    + (size_t)NROWS * 64;    // NROWS*64
  float* pA   = out1 + (size_t)NROWS * 64;    // nk*65536*16
  float* pL   = pA   + (size_t)nk * 65536 * 16;  // nk*65536

  build_x_kernel<<<4096, 256, 0, stream>>>(inputs, emb, x, keep);

  for (int i = 0; i < 2; ++i) {
    qkv_kernel<<<2048, 64, 0, stream>>>(
        x, wq + i * 4096, wqb + i * 64, wk + i * 4096, wkb + i * 64,
        wv + i * 4096, wvb + i * 64, q, k, v);
    if (nk == 16) {
      attn_partial_kernel<64><<<dim3(128, 16), 256, 0, stream>>>(
          q, k, v, keep, pA, pL);
    } else {
      attn_partial_kernel<128><<<dim3(128, 8), 256, 0, stream>>>(
          q, k, v, keep, pA, pL);
    }
    wo_ln1_kernel<<<1024, 256, 0, stream>>>(
        pA, pL, x, wo + i * 4096, l1g + i * 64, l1b + i * 64, keep, out1, nk);
    ffn_fused_kernel<<<1024, 256, 0, stream>>>(
        out1, fw1 + i * 16384, fw2 + i * 16384, l2g + i * 64, l2b + i * 64,
        keep, x);
  }

  init_out_kernel<<<1, 64, 0, stream>>>(obias, out);
  classifier_kernel<<<512, 256, 0, stream>>>(x, cw1, cb1, cw2, cb2, cw3, cb3, out);
}

// Round 13
// 413.923 us; speedup vs baseline: 1.8031x; 1.8031x over previous
//
#include <hip/hip_runtime.h>
#include <hip/hip_bf16.h>
#include <math.h>

// Problem constants (from reference): B=16, S=1024, D=64, H=4, DFF=256, L=2
#define BB 16
#define SS 1024
#define DD 64
#define HH 4
#define DEPTH 16
#define DFF 256
#define NROWS (BB*SS)        // 16384 token rows
#define EPSV 1e-6f

typedef float f32x2 __attribute__((ext_vector_type(2)));

// Packed fp32 FMA: c.lo += a.lo*b.lo ; c.hi += a.hi*b.hi  (one VOP3P instr).
// R10 LESSON: pk_fma halves instruction count (-7% attn).
// R11 LESSON: __launch_bounds__ min-waves arg is a VGPR *cap*: (256,8) forced
// 32 VGPR -> total spill (FETCH 172MB, 3.4x slowdown). Request occupancy via
// GRID SHAPE, never via a bounds value tighter than the kernel's live state.
__device__ __forceinline__ void pk_fma(f32x2& c, f32x2 a, f32x2 b) {
  asm("v_pk_fma_f32 %0, %1, %2, %0" : "+v"(c) : "v"(a), "v"(b));
}
__device__ __forceinline__ f32x2 lo2(float4 v) { f32x2 r; r.x = v.x; r.y = v.y; return r; }
__device__ __forceinline__ f32x2 hi2(float4 v) { f32x2 r; r.x = v.z; r.y = v.w; return r; }

// Broadcast lane kk of x to all lanes via v_readlane (no LDS traffic).
// R5/R7: readlane-with-one-live-scalar is the only validated broadcast when
// ~64+ weight VGPRs are live. R8: no LDS-dependent branch at loop head.
// R9: manual LDS software-pipelining is neutral.
__device__ __forceinline__ float bcast(float x, int kk) {
  return __int_as_float(__builtin_amdgcn_readlane(__float_as_int(x), kk));
}

// ---------------------------------------------------------------------------
// Kernel 1: build x (B,S,D) and keep (B,S).
// ---------------------------------------------------------------------------
__global__ __launch_bounds__(256) void build_x_kernel(
    const float* __restrict__ inputs, const float* __restrict__ emb,
    float* __restrict__ x, float* __restrict__ keep) {
  int gid = blockIdx.x * 256 + threadIdx.x;   // over NROWS*64 elements
  int row = gid >> 6;
  int d = gid & 63;
  int s = row & (SS - 1);
  float vin = inputs[row];
  bool nan = __builtin_isnan(vin);
  float kp = nan ? 0.0f : 1.0f;
  if (d == 0) keep[row] = kp;
  float val;
  if (d < 63) {
    const float scale = 7.93725393319377f * 8.0f;  // sqrt(63)*sqrt(64)
    val = emb[s * 63 + d] * scale;
  } else {
    val = nan ? 0.0f : vin;
  }
  x[row * 64 + d] = val * kp;
}

// ---------------------------------------------------------------------------
// Kernel 2: QKV projection, weights-in-VGPR + readlane broadcast (R4 form —
// best measured). q,k,v layout (B,H,S,DEPTH).
// ---------------------------------------------------------------------------
__global__ __launch_bounds__(64, 2) void qkv_kernel(
    const float* __restrict__ xin,
    const float* __restrict__ wq, const float* __restrict__ wqb,
    const float* __restrict__ wk, const float* __restrict__ wkb,
    const float* __restrict__ wv, const float* __restrict__ wvb,
    float* __restrict__ q, float* __restrict__ k, float* __restrict__ v) {
  int lane = threadIdx.x;
  float wqc[64], wkc[64], wvc[64];
#pragma unroll
  for (int kk = 0; kk < 64; ++kk) {
    wqc[kk] = wq[kk * 64 + lane];
    wkc[kk] = wk[kk * 64 + lane];
    wvc[kk] = wv[kk * 64 + lane];
  }
  float bq = wqb[lane], bk = wkb[lane], bv = wvb[lane];
  int h = lane >> 4, dep = lane & 15;
  int row0 = blockIdx.x * 8;
  for (int r = row0; r < row0 + 8; ++r) {
    float xr = xin[r * 64 + lane];
    float qa0 = 0.f, qa1 = 0.f, ka0 = 0.f, ka1 = 0.f, va0 = 0.f, va1 = 0.f;
#pragma unroll
    for (int kk = 0; kk < 64; kk += 2) {
      float x0 = bcast(xr, kk);
      float x1 = bcast(xr, kk + 1);
      qa0 = fmaf(x0, wqc[kk], qa0); qa1 = fmaf(x1, wqc[kk + 1], qa1);
      ka0 = fmaf(x0, wkc[kk], ka0); ka1 = fmaf(x1, wkc[kk + 1], ka1);
      va0 = fmaf(x0, wvc[kk], va0); va1 = fmaf(x1, wvc[kk + 1], va1);
    }
    int b = r >> 10, s = r & (SS - 1);
    size_t o = (size_t)(((b * HH + h) * SS + s)) * DEPTH + dep;
    q[o] = qa0 + qa1 + bq;
    k[o] = ka0 + ka1 + bk;
    v[o] = va0 + va1 + bv;
  }
}

// ---------------------------------------------------------------------------
// Kernel 3: split-K attention partials, 2 queries/thread, K/V chunk in LDS,
// packed-fp32 math. KCH=64 -> 16 chunks, 2048 blocks, 8 blocks/CU: the
// occupancy comes from GRID SHAPE; bounds stay (256,4) so the allocator
// keeps ~48 VGPR (R11 lesson). KCH=128 -> R10 8-chunk fallback.
// q pre-scaled by 0.25 (exact pow2). No max-subtraction softmax (exact for
// this data); partials combine by plain addition -> deterministic split-K.
// ---------------------------------------------------------------------------
template <int KCH>
__global__ __launch_bounds__(256, 4) void attn_partial_kernel(
    const float* __restrict__ q, const float* __restrict__ k,
    const float* __restrict__ v, const float* __restrict__ keep,
    float* __restrict__ pA, float* __restrict__ pL) {
  __shared__ __align__(16) float klds[KCH * DEPTH];
  __shared__ __align__(16) float vlds[KCH * DEPTH];
  __shared__ float kplds[KCH];
  int tid = threadIdx.x;
  int p = blockIdx.x * 256 + tid;                // pair id [0, 32768)
  int c = blockIdx.y;                            // key chunk
  int bh = p >> 9;                               // 512 pairs per (b,h)
  int s0 = p & 511;
  int b = bh >> 2;

  const float4* kbase = (const float4*)(k + ((size_t)bh * SS + c * KCH) * DEPTH);
  const float4* vbase = (const float4*)(v + ((size_t)bh * SS + c * KCH) * DEPTH);
#pragma unroll
  for (int i = 0; i < KCH * 4 / 256; ++i) {
    ((float4*)klds)[tid + i * 256] = kbase[tid + i * 256];
    ((float4*)vlds)[tid + i * 256] = vbase[tid + i * 256];
  }
  if (tid < KCH) kplds[tid] = keep[b * SS + c * KCH + tid];
  __syncthreads();

  size_t rowA = (size_t)bh * SS + s0;
  size_t rowB = rowA + 512;
  const float4* qa4 = (const float4*)(q + rowA * DEPTH);
  const float4* qb4 = (const float4*)(q + rowB * DEPTH);
  f32x2 qA[8], qB[8];
#pragma unroll
  for (int i = 0; i < 4; ++i) {
    float4 ta = qa4[i], tb = qb4[i];
    qA[2 * i].x     = ta.x * 0.25f; qA[2 * i].y     = ta.y * 0.25f;
    qA[2 * i + 1].x = ta.z * 0.25f; qA[2 * i + 1].y = ta.w * 0.25f;
    qB[2 * i].x     = tb.x * 0.25f; qB[2 * i].y     = tb.y * 0.25f;
    qB[2 * i + 1].x = tb.z * 0.25f; qB[2 * i + 1].y = tb.w * 0.25f;
  }
  f32x2 z2; z2.x = 0.f; z2.y = 0.f;
  f32x2 aA[8], aB[8];
#pragma unroll
  for (int i = 0; i < 8; ++i) { aA[i] = z2; aB[i] = z2; }
  float lA = 0.0f, lB = 0.0f;
  const float4* kl4 = (const float4*)klds;
  const float4* vl4 = (const float4*)vlds;
  for (int j = 0; j < KCH; ++j) {
    float4 k0 = kl4[j * 4 + 0], k1 = kl4[j * 4 + 1];
    float4 k2 = kl4[j * 4 + 2], k3 = kl4[j * 4 + 3];
    float4 v0 = vl4[j * 4 + 0], v1 = vl4[j * 4 + 1];
    float4 v2 = vl4[j * 4 + 2], v3 = vl4[j * 4 + 3];
    float kpj = kplds[j];
    f32x2 kk0 = lo2(k0), kk1 = hi2(k0), kk2 = lo2(k1), kk3 = hi2(k1);
    f32x2 kk4 = lo2(k2), kk5 = hi2(k2), kk6 = lo2(k3), kk7 = hi2(k3);
    f32x2 dA = z2, dB = z2;
    pk_fma(dA, qA[0], kk0); pk_fma(dB, qB[0], kk0);
    pk_fma(dA, qA[1], kk1); pk_fma(dB, qB[1], kk1);
    pk_fma(dA, qA[2], kk2); pk_fma(dB, qB[2], kk2);
    pk_fma(dA, qA[3], kk3); pk_fma(dB, qB[3], kk3);
    pk_fma(dA, qA[4], kk4); pk_fma(dB, qB[4], kk4);
    pk_fma(dA, qA[5], kk5); pk_fma(dB, qB[5], kk5);
    pk_fma(dA, qA[6], kk6); pk_fma(dB, qB[6], kk6);
    pk_fma(dA, qA[7], kk7); pk_fma(dB, qB[7], kk7);
    float pa = __expf(dA.x + dA.y) * kpj;
    float pb = __expf(dB.x + dB.y) * kpj;
    lA += pa; lB += pb;
    f32x2 pa2, pb2;
    pa2.x = pa; pa2.y = pa; pb2.x = pb; pb2.y = pb;
    f32x2 vv0 = lo2(v0), vv1 = hi2(v0), vv2 = lo2(v1), vv3 = hi2(v1);
    f32x2 vv4 = lo2(v2), vv5 = hi2(v2), vv6 = lo2(v3), vv7 = hi2(v3);
    pk_fma(aA[0], pa2, vv0); pk_fma(aB[0], pb2, vv0);
    pk_fma(aA[1], pa2, vv1); pk_fma(aB[1], pb2, vv1);
    pk_fma(aA[2], pa2, vv2); pk_fma(aB[2], pb2, vv2);
    pk_fma(aA[3], pa2, vv3); pk_fma(aB[3], pb2, vv3);
    pk_fma(aA[4], pa2, vv4); pk_fma(aB[4], pb2, vv4);
    pk_fma(aA[5], pa2, vv5); pk_fma(aB[5], pb2, vv5);
    pk_fma(aA[6], pa2, vv6); pk_fma(aB[6], pb2, vv6);
    pk_fma(aA[7], pa2, vv7); pk_fma(aB[7], pb2, vv7);
  }
  size_t oA = ((size_t)c << 16) + rowA;
  size_t oB = ((size_t)c << 16) + rowB;
  pL[oA] = lA; pL[oB] = lB;
  float4* o4a = (float4*)(pA + oA * 16);
  o4a[0] = make_float4(aA[0].x, aA[0].y, aA[1].x, aA[1].y);
  o4a[1] = make_float4(aA[2].x, aA[2].y, aA[3].x, aA[3].y);
  o4a[2] = make_float4(aA[4].x, aA[4].y, aA[5].x, aA[5].y);
  o4a[3] = make_float4(aA[6].x, aA[6].y, aA[7].x, aA[7].y);
  float4* o4b = (float4*)(pA + oB * 16);
  o4b[0] = make_float4(aB[0].x, aB[0].y, aB[1].x, aB[1].y);
  o4b[1] = make_float4(aB[2].x, aB[2].y, aB[3].x, aB[3].y);
  o4b[2] = make_float4(aB[4].x, aB[4].y, aB[5].x, aB[5].y);
  o4b[3] = make_float4(aB[6].x, aB[6].y, aB[7].x, aB[7].y);
}

// ---------------------------------------------------------------------------
// Kernel 4: out1 = LayerNorm(x + ctx@wo) * keep, fused split-K combine
// (nk = runtime chunk count). R4 proven form: wo column in VGPRs, readlane.
// ---------------------------------------------------------------------------
__global__ __launch_bounds__(256) void wo_ln1_kernel(
    const float* __restrict__ pA, const float* __restrict__ pL,
    const float* __restrict__ xin,
    const float* __restrict__ wo, const float* __restrict__ g,
    const float* __restrict__ bta, const float* __restrict__ keep,
    float* __restrict__ out1, int nk) {
  int tid = threadIdx.x;
  int lane = tid & 63;
  float woc[64];
#pragma unroll
  for (int kk = 0; kk < 64; ++kk) woc[kk] = wo[kk * 64 + lane];
  float gg = g[lane], bb = bta[lane];
  int wave = tid >> 6;
  int row0 = blockIdx.x * 16 + wave * 4;
  for (int r = row0; r < row0 + 4; ++r) {
    int b = r >> 10, s = r & (SS - 1);
    int h = lane >> 4, dep = lane & 15;
    size_t rowi = ((size_t)(b * HH + h) << 10) + s;
    float num = 0.0f, den = 0.0f;
    for (int c = 0; c < nk; ++c) {
      num += pA[(((size_t)c << 16) + rowi) * 16 + dep];
      den += pL[((size_t)c << 16) + rowi];
    }
    float cr = num * keep[r] / den;   // keep==0 -> exact 0 (den>0 always)
    float a0 = 0.f, a1 = 0.f;
#pragma unroll
    for (int kk = 0; kk < 64; kk += 2) {
      a0 = fmaf(bcast(cr, kk), woc[kk], a0);
      a1 = fmaf(bcast(cr, kk + 1), woc[kk + 1], a1);
    }
    float t = a0 + a1 + xin[r * 64 + lane];
    float sum = t;
#pragma unroll
    for (int off = 32; off; off >>= 1) sum += __shfl_xor(sum, off, 64);
    float mean = sum * (1.0f / 64.0f);
    float dv = t - mean;
    float sq = dv * dv;
#pragma unroll
    for (int off = 32; off; off >>= 1) sq += __shfl_xor(sq, off, 64);
    float var = sq * (1.0f / 64.0f);
    float o = dv * rsqrtf(var + EPSV) * gg + bb;
    out1[r * 64 + lane] = o * keep[r];
  }
}

// ---------------------------------------------------------------------------
// Kernel 5: fused FFN: x = LayerNorm(out1 + relu(out1@W1)@W2) * keep.
// R4 proven form: readlane broadcasts in both phases.
// ---------------------------------------------------------------------------
__global__ __launch_bounds__(256) void ffn_fused_kernel(
    const float* __restrict__ out1, const float* __restrict__ w1,
    const float* __restrict__ w2, const float* __restrict__ g,
    const float* __restrict__ bta, const float* __restrict__ keep,
    float* __restrict__ xout) {
  __shared__ float part[4][4][64];   // [row-in-group][wave][lane]
  int tid = threadIdx.x, wave = tid >> 6, lane = tid & 63;
  float w1c[64], w2c[64];
#pragma unroll
  for (int kk = 0; kk < 64; ++kk)
    w1c[kk] = w1[kk * 256 + wave * 64 + lane];     // W1[kk][wave*64+lane]
#pragma unroll
  for (int j = 0; j < 64; ++j)
    w2c[j] = w2[(wave * 64 + j) * 64 + lane];      // W2[wave*64+j][lane]
  float gg = g[lane], bb = bta[lane];
  int row0 = blockIdx.x * 16;
  for (int grp = 0; grp < 4; ++grp) {
    int rbase = row0 + grp * 4;
    float xr0 = out1[(rbase + 0) * 64 + lane];
    float xr1 = out1[(rbase + 1) * 64 + lane];
    float xr2 = out1[(rbase + 2) * 64 + lane];
    float xr3 = out1[(rbase + 3) * 64 + lane];
    float xrs[4] = {xr0, xr1, xr2, xr3};
#pragma unroll
    for (int r = 0; r < 4; ++r) {
      float h0 = 0.f, h1 = 0.f;
#pragma unroll
      for (int kk = 0; kk < 64; kk += 2) {
        h0 = fmaf(bcast(xrs[r], kk), w1c[kk], h0);
        h1 = fmaf(bcast(xrs[r], kk + 1), w1c[kk + 1], h1);
      }
      float hv = fmaxf(h0 + h1, 0.0f);
      float y0 = 0.f, y1 = 0.f;
#pragma unroll
      for (int j = 0; j < 64; j += 2) {
        y0 = fmaf(bcast(hv, j), w2c[j], y0);
        y1 = fmaf(bcast(hv, j + 1), w2c[j + 1], y1);
      }
      part[r][wave][lane] = y0 + y1;
    }
    __syncthreads();
    // wave w finishes row rbase+w (compile-time select, no scratch)
    float xres = (wave == 0) ? xr0 : (wave == 1) ? xr1 : (wave == 2) ? xr2 : xr3;
    float t = part[wave][0][lane] + part[wave][1][lane] +
              part[wave][2][lane] + part[wave][3][lane] + xres;
    float sum = t;
#pragma unroll
    for (int off = 32; off; off >>= 1) sum += __shfl_xor(sum, off, 64);
    float mean = sum * (1.0f / 64.0f);
    float dv = t - mean;
    float sq = dv * dv;
#pragma unroll
    for (int off = 32; off; off >>= 1) sq += __shfl_xor(sq, off, 64);
    float var = sq * (1.0f / 64.0f);
    float o = dv * rsqrtf(var + EPSV) * gg + bb;
    xout[(rbase + wave) * 64 + lane] = o * keep[rbase + wave];
    __syncthreads();   // before next group overwrites part
  }
}

// ---------------------------------------------------------------------------
// Kernel 6: init output: out[b] = out_bias[0]
// ---------------------------------------------------------------------------
__global__ void init_out_kernel(const float* __restrict__ out_bias,
                                float* __restrict__ out) {
  if (threadIdx.x < BB) out[threadIdx.x] = out_bias[0];
}

// ---------------------------------------------------------------------------
// Kernel 7: classifier, weights-in-VGPR + readlane (R4 proven form).
// ---------------------------------------------------------------------------
__global__ __launch_bounds__(256, 3) void classifier_kernel(
    const float* __restrict__ x,
    const float* __restrict__ w1, const float* __restrict__ b1,
    const float* __restrict__ w2, const float* __restrict__ b2,
    const float* __restrict__ w3, const float* __restrict__ b3,
    float* __restrict__ out) {
  int tid = threadIdx.x;
  int lane = tid & 63, wave = tid >> 6;
  float w1c[64], w2c[64];
#pragma unroll
  for (int kk = 0; kk < 64; ++kk) {
    w1c[kk] = w1[kk * 64 + lane];
    w2c[kk] = w2[kk * 64 + lane];
  }
  float w3d = w3[lane];
  float bb1 = b1[lane], bb2 = b2[lane], b3v = b3[0];
  int row0 = blockIdx.x * 32 + wave * 8;
  float wavesum = 0.0f;
  for (int r = row0; r < row0 + 8; ++r) {
    float xr = x[r * 64 + lane];
    float h1a = 0.f, h1b = 0.f;
#pragma unroll
    for (int kk = 0; kk < 64; kk += 2) {
      h1a = fmaf(bcast(xr, kk), w1c[kk], h1a);
      h1b = fmaf(bcast(xr, kk + 1), w1c[kk + 1], h1b);
    }
    float h1 = fmaxf(h1a + h1b + bb1, 0.0f);
    float h2a = 0.f, h2b = 0.f;
#pragma unroll
    for (int kk = 0; kk < 64; kk += 2) {
      h2a = fmaf(bcast(h1, kk), w2c[kk], h2a);
      h2b = fmaf(bcast(h1, kk + 1), w2c[kk + 1], h2b);
    }
    float h2 = fmaxf(h2a + h2b + bb2, 0.0f);
    float p = h2 * w3d;
#pragma unroll
    for (int off = 32; off; off >>= 1) p += __shfl_xor(p, off, 64);
    wavesum += p + b3v;
  }
  if (lane == 0) {
    int b = row0 >> 10;
    atomicAdd(&out[b], wavesum);
  }
}

// ---------------------------------------------------------------------------
extern "C" void kernel_launch(void* const* d_in, const int* in_sizes, int n_in,
                              void* d_out, int out_size, void* d_ws, size_t ws_size,
                              hipStream_t stream) {
  const float* inputs = (const float*)d_in[0];
  const float* emb    = (const float*)d_in[1];
  const float* wq     = (const float*)d_in[2];
  const float* wqb    = (const float*)d_in[3];
  const float* wk     = (const float*)d_in[4];
  const float* wkb    = (const float*)d_in[5];
  const float* wv     = (const float*)d_in[6];
  const float* wvb    = (const float*)d_in[7];
  const float* wo     = (const float*)d_in[8];
  const float* fw1    = (const float*)d_in[9];
  const float* fw2    = (const float*)d_in[10];
  const float* l1g    = (const float*)d_in[11];
  const float* l1b    = (const float*)d_in[12];
  const float* l2g    = (const float*)d_in[13];
  const float* l2b    = (const float*)d_in[14];
  const float* cw1    = (const float*)d_in[15];
  const float* cb1    = (const float*)d_in[16];
  const float* cw2    = (const float*)d_in[17];
  const float* cb2    = (const float*)d_in[18];
  const float* cw3    = (const float*)d_in[19];
  const float* cb3    = (const float*)d_in[20];
  const float* obias  = (const float*)d_in[21];
  float* out = (float*)d_out;

  // Choose split-K factor by available workspace: NK=16 needs ~92 MB,
  // NK=8 (R10 fallback) ~56 MB. ws_size is fixed per harness, so every
  // call takes the same path (graph-capture safe).
  size_t base_floats = (size_t)NROWS * 64 * 5 + NROWS;   // x,q,k,v,out1,keep
  size_t need16 = (base_floats + (size_t)16 * 65536 * 17) * 4;
  int nk = (ws_size >= need16) ? 16 : 8;

  float* ws   = (float*)d_ws;
  float* x    = ws;                           // NROWS*64
  float* keep = x    + (size_t)NROWS * 64;    // NROWS
  float* q    = keep + NROWS;                 // NROWS*64  (B,H,S,DEPTH)
  float* k    = q    + (size_t)NROWS * 64;
  float* v    = k    + (size_t)NROWS * 64;
  float* out1 = v    + (size_t)NROWS * 64;    // NROWS*64
  float* pA   = out1 + (size_t)NROWS * 64;    // nk*65536*16
  float* pL   = pA   + (size_t)nk * 65536 * 16;  // nk*65536

  build_x_kernel<<<4096, 256, 0, stream>>>(inputs, emb, x, keep);

  for (int i = 0; i < 2; ++i) {
    qkv_kernel<<<2048, 64, 0, stream>>>(
        x, wq + i * 4096, wqb + i * 64, wk + i * 4096, wkb + i * 64,
        wv + i * 4096, wvb + i * 64, q, k, v);
    if (nk == 16) {
      attn_partial_kernel<64><<<dim3(128, 16), 256, 0, stream>>>(
          q, k, v, keep, pA, pL);
    } else {
      attn_partial_kernel<128><<<dim3(128, 8), 256, 0, stream>>>(
          q, k, v, keep, pA, pL);
    }
    wo_ln1_kernel<<<1024, 256, 0, stream>>>(
        pA, pL, x, wo + i * 4096, l1g + i * 64, l1b + i * 64, keep, out1, nk);
    ffn_fused_kernel<<<1024, 256, 0, stream>>>(
        out1, fw1 + i * 16384, fw2 + i * 16384, l2g + i * 64, l2b + i * 64,
        keep, x);
  }

  init_out_kernel<<<1, 64, 0, stream>>>(obias, out);
  classifier_kernel<<<512, 256, 0, stream>>>(x, cw1, cb1, cw2, cb2, cw3, cb3, out);
}

// Round 14
// 411.278 us; speedup vs baseline: 1.8147x; 1.0064x over previous
//
#include <hip/hip_runtime.h>
#include <hip/hip_bf16.h>
#include <math.h>

// Problem constants (from reference): B=16, S=1024, D=64, H=4, DFF=256, L=2
#define BB 16
#define SS 1024
#define DD 64
#define HH 4
#define DEPTH 16
#define DFF 256
#define NROWS (BB*SS)        // 16384 token rows
#define EPSV 1e-6f

typedef float f32x2 __attribute__((ext_vector_type(2)));

// Packed fp32 FMA: c.lo += a.lo*b.lo ; c.hi += a.hi*b.hi  (one VOP3P instr).
// R10: pk_fma halves instruction count (-7% attn).
// R11: __launch_bounds__ min-waves arg is a VGPR *cap*: (256,8) forced 32
// VGPR -> total spill. Occupancy comes from GRID SHAPE, not bounds.
// R13: runtime-bound reduction loops don't unroll -> serial load-add chain
// (~200cyc/load). Keep reduction trip counts compile-time (template).
__device__ __forceinline__ void pk_fma(f32x2& c, f32x2 a, f32x2 b) {
  asm("v_pk_fma_f32 %0, %1, %2, %0" : "+v"(c) : "v"(a), "v"(b));
}
__device__ __forceinline__ f32x2 lo2(float4 v) { f32x2 r; r.x = v.x; r.y = v.y; return r; }
__device__ __forceinline__ f32x2 hi2(float4 v) { f32x2 r; r.x = v.z; r.y = v.w; return r; }

// Broadcast lane kk of x to all lanes via v_readlane (no LDS traffic).
// R5/R7: readlane-with-one-live-scalar is the only validated broadcast when
// ~64+ weight VGPRs are live. R8: no LDS-dependent branch at loop head.
// R9: manual LDS software-pipelining is neutral.
__device__ __forceinline__ float bcast(float x, int kk) {
  return __int_as_float(__builtin_amdgcn_readlane(__float_as_int(x), kk));
}

// ---------------------------------------------------------------------------
// Kernel 1: build x (B,S,D) and keep (B,S).
// ---------------------------------------------------------------------------
__global__ __launch_bounds__(256) void build_x_kernel(
    const float* __restrict__ inputs, const float* __restrict__ emb,
    float* __restrict__ x, float* __restrict__ keep) {
  int gid = blockIdx.x * 256 + threadIdx.x;   // over NROWS*64 elements
  int row = gid >> 6;
  int d = gid & 63;
  int s = row & (SS - 1);
  float vin = inputs[row];
  bool nan = __builtin_isnan(vin);
  float kp = nan ? 0.0f : 1.0f;
  if (d == 0) keep[row] = kp;
  float val;
  if (d < 63) {
    const float scale = 7.93725393319377f * 8.0f;  // sqrt(63)*sqrt(64)
    val = emb[s * 63 + d] * scale;
  } else {
    val = nan ? 0.0f : vin;
  }
  x[row * 64 + d] = val * kp;
}

// ---------------------------------------------------------------------------
// Kernel 2: QKV projection, weights-in-VGPR + readlane broadcast (R4 form —
// best measured). q,k,v layout (B,H,S,DEPTH).
// ---------------------------------------------------------------------------
__global__ __launch_bounds__(64, 2) void qkv_kernel(
    const float* __restrict__ xin,
    const float* __restrict__ wq, const float* __restrict__ wqb,
    const float* __restrict__ wk, const float* __restrict__ wkb,
    const float* __restrict__ wv, const float* __restrict__ wvb,
    float* __restrict__ q, float* __restrict__ k, float* __restrict__ v) {
  int lane = threadIdx.x;
  float wqc[64], wkc[64], wvc[64];
#pragma unroll
  for (int kk = 0; kk < 64; ++kk) {
    wqc[kk] = wq[kk * 64 + lane];
    wkc[kk] = wk[kk * 64 + lane];
    wvc[kk] = wv[kk * 64 + lane];
  }
  float bq = wqb[lane], bk = wkb[lane], bv = wvb[lane];
  int h = lane >> 4, dep = lane & 15;
  int row0 = blockIdx.x * 8;
  for (int r = row0; r < row0 + 8; ++r) {
    float xr = xin[r * 64 + lane];
    float qa0 = 0.f, qa1 = 0.f, ka0 = 0.f, ka1 = 0.f, va0 = 0.f, va1 = 0.f;
#pragma unroll
    for (int kk = 0; kk < 64; kk += 2) {
      float x0 = bcast(xr, kk);
      float x1 = bcast(xr, kk + 1);
      qa0 = fmaf(x0, wqc[kk], qa0); qa1 = fmaf(x1, wqc[kk + 1], qa1);
      ka0 = fmaf(x0, wkc[kk], ka0); ka1 = fmaf(x1, wkc[kk + 1], ka1);
      va0 = fmaf(x0, wvc[kk], va0); va1 = fmaf(x1, wvc[kk + 1], va1);
    }
    int b = r >> 10, s = r & (SS - 1);
    size_t o = (size_t)(((b * HH + h) * SS + s)) * DEPTH + dep;
    q[o] = qa0 + qa1 + bq;
    k[o] = ka0 + ka1 + bk;
    v[o] = va0 + va1 + bv;
  }
}

// ---------------------------------------------------------------------------
// Kernel 3: split-K attention partials, 2 queries/thread, K/V chunk in LDS,
// packed-fp32 math. KCH=64 -> 16 chunks, 2048 blocks, 8 blocks/CU (grid-
// shape occupancy; bounds stay (256,4), VGPR~48 — R11 lesson). KCH=128 ->
// R10 8-chunk fallback. q pre-scaled by 0.25 (exact pow2). No
// max-subtraction softmax (exact for this data); partials combine by plain
// addition -> deterministic split-K.
// ---------------------------------------------------------------------------
template <int KCH>
__global__ __launch_bounds__(256, 4) void attn_partial_kernel(
    const float* __restrict__ q, const float* __restrict__ k,
    const float* __restrict__ v, const float* __restrict__ keep,
    float* __restrict__ pA, float* __restrict__ pL) {
  __shared__ __align__(16) float klds[KCH * DEPTH];
  __shared__ __align__(16) float vlds[KCH * DEPTH];
  __shared__ float kplds[KCH];
  int tid = threadIdx.x;
  int p = blockIdx.x * 256 + tid;                // pair id [0, 32768)
  int c = blockIdx.y;                            // key chunk
  int bh = p >> 9;                               // 512 pairs per (b,h)
  int s0 = p & 511;
  int b = bh >> 2;

  const float4* kbase = (const float4*)(k + ((size_t)bh * SS + c * KCH) * DEPTH);
  const float4* vbase = (const float4*)(v + ((size_t)bh * SS + c * KCH) * DEPTH);
#pragma unroll
  for (int i = 0; i < KCH * 4 / 256; ++i) {
    ((float4*)klds)[tid + i * 256] = kbase[tid + i * 256];
    ((float4*)vlds)[tid + i * 256] = vbase[tid + i * 256];
  }
  if (tid < KCH) kplds[tid] = keep[b * SS + c * KCH + tid];
  __syncthreads();

  size_t rowA = (size_t)bh * SS + s0;
  size_t rowB = rowA + 512;
  const float4* qa4 = (const float4*)(q + rowA * DEPTH);
  const float4* qb4 = (const float4*)(q + rowB * DEPTH);
  f32x2 qA[8], qB[8];
#pragma unroll
  for (int i = 0; i < 4; ++i) {
    float4 ta = qa4[i], tb = qb4[i];
    qA[2 * i].x     = ta.x * 0.25f; qA[2 * i].y     = ta.y * 0.25f;
    qA[2 * i + 1].x = ta.z * 0.25f; qA[2 * i + 1].y = ta.w * 0.25f;
    qB[2 * i].x     = tb.x * 0.25f; qB[2 * i].y     = tb.y * 0.25f;
    qB[2 * i + 1].x = tb.z * 0.25f; qB[2 * i + 1].y = tb.w * 0.25f;
  }
  f32x2 z2; z2.x = 0.f; z2.y = 0.f;
  f32x2 aA[8], aB[8];
#pragma unroll
  for (int i = 0; i < 8; ++i) { aA[i] = z2; aB[i] = z2; }
  float lA = 0.0f, lB = 0.0f;
  const float4* kl4 = (const float4*)klds;
  const float4* vl4 = (const float4*)vlds;
  for (int j = 0; j < KCH; ++j) {
    float4 k0 = kl4[j * 4 + 0], k1 = kl4[j * 4 + 1];
    float4 k2 = kl4[j * 4 + 2], k3 = kl4[j * 4 + 3];
    float4 v0 = vl4[j * 4 + 0], v1 = vl4[j * 4 + 1];
    float4 v2 = vl4[j * 4 + 2], v3 = vl4[j * 4 + 3];
    float kpj = kplds[j];
    f32x2 kk0 = lo2(k0), kk1 = hi2(k0), kk2 = lo2(k1), kk3 = hi2(k1);
    f32x2 kk4 = lo2(k2), kk5 = hi2(k2), kk6 = lo2(k3), kk7 = hi2(k3);
    f32x2 dA = z2, dB = z2;
    pk_fma(dA, qA[0], kk0); pk_fma(dB, qB[0], kk0);
    pk_fma(dA, qA[1], kk1); pk_fma(dB, qB[1], kk1);
    pk_fma(dA, qA[2], kk2); pk_fma(dB, qB[2], kk2);
    pk_fma(dA, qA[3], kk3); pk_fma(dB, qB[3], kk3);
    pk_fma(dA, qA[4], kk4); pk_fma(dB, qB[4], kk4);
    pk_fma(dA, qA[5], kk5); pk_fma(dB, qB[5], kk5);
    pk_fma(dA, qA[6], kk6); pk_fma(dB, qB[6], kk6);
    pk_fma(dA, qA[7], kk7); pk_fma(dB, qB[7], kk7);
    float pa = __expf(dA.x + dA.y) * kpj;
    float pb = __expf(dB.x + dB.y) * kpj;
    lA += pa; lB += pb;
    f32x2 pa2, pb2;
    pa2.x = pa; pa2.y = pa; pb2.x = pb; pb2.y = pb;
    f32x2 vv0 = lo2(v0), vv1 = hi2(v0), vv2 = lo2(v1), vv3 = hi2(v1);
    f32x2 vv4 = lo2(v2), vv5 = hi2(v2), vv6 = lo2(v3), vv7 = hi2(v3);
    pk_fma(aA[0], pa2, vv0); pk_fma(aB[0], pb2, vv0);
    pk_fma(aA[1], pa2, vv1); pk_fma(aB[1], pb2, vv1);
    pk_fma(aA[2], pa2, vv2); pk_fma(aB[2], pb2, vv2);
    pk_fma(aA[3], pa2, vv3); pk_fma(aB[3], pb2, vv3);
    pk_fma(aA[4], pa2, vv4); pk_fma(aB[4], pb2, vv4);
    pk_fma(aA[5], pa2, vv5); pk_fma(aB[5], pb2, vv5);
    pk_fma(aA[6], pa2, vv6); pk_fma(aB[6], pb2, vv6);
    pk_fma(aA[7], pa2, vv7); pk_fma(aB[7], pb2, vv7);
  }
  size_t oA = ((size_t)c << 16) + rowA;
  size_t oB = ((size_t)c << 16) + rowB;
  pL[oA] = lA; pL[oB] = lB;
  float4* o4a = (float4*)(pA + oA * 16);
  o4a[0] = make_float4(aA[0].x, aA[0].y, aA[1].x, aA[1].y);
  o4a[1] = make_float4(aA[2].x, aA[2].y, aA[3].x, aA[3].y);
  o4a[2] = make_float4(aA[4].x, aA[4].y, aA[5].x, aA[5].y);
  o4a[3] = make_float4(aA[6].x, aA[6].y, aA[7].x, aA[7].y);
  float4* o4b = (float4*)(pA + oB * 16);
  o4b[0] = make_float4(aB[0].x, aB[0].y, aB[1].x, aB[1].y);
  o4b[1] = make_float4(aB[2].x, aB[2].y, aB[3].x, aB[3].y);
  o4b[2] = make_float4(aB[4].x, aB[4].y, aB[5].x, aB[5].y);
  o4b[3] = make_float4(aB[6].x, aB[6].y, aB[7].x, aB[7].y);
}

// ---------------------------------------------------------------------------
// Kernel 4: out1 = LayerNorm(x + ctx@wo) * keep, fused split-K combine.
// Templated on NK so the combine loop UNROLLS (R13 lesson: runtime bound ->
// serial ~200cyc load-add chain; compile-time -> pipelined loads).
// R4 proven form: wo column in VGPRs, readlane broadcast.
// ---------------------------------------------------------------------------
template <int NK>
__global__ __launch_bounds__(256) void wo_ln1_kernel(
    const float* __restrict__ pA, const float* __restrict__ pL,
    const float* __restrict__ xin,
    const float* __restrict__ wo, const float* __restrict__ g,
    const float* __restrict__ bta, const float* __restrict__ keep,
    float* __restrict__ out1) {
  int tid = threadIdx.x;
  int lane = tid & 63;
  float woc[64];
#pragma unroll
  for (int kk = 0; kk < 64; ++kk) woc[kk] = wo[kk * 64 + lane];
  float gg = g[lane], bb = bta[lane];
  int wave = tid >> 6;
  int row0 = blockIdx.x * 16 + wave * 4;
  for (int r = row0; r < row0 + 4; ++r) {
    int b = r >> 10, s = r & (SS - 1);
    int h = lane >> 4, dep = lane & 15;
    size_t rowi = ((size_t)(b * HH + h) << 10) + s;
    float num = 0.0f, den = 0.0f;
#pragma unroll
    for (int c = 0; c < NK; ++c) {
      num += pA[(((size_t)c << 16) + rowi) * 16 + dep];
      den += pL[((size_t)c << 16) + rowi];
    }
    float cr = num * keep[r] / den;   // keep==0 -> exact 0 (den>0 always)
    float a0 = 0.f, a1 = 0.f;
#pragma unroll
    for (int kk = 0; kk < 64; kk += 2) {
      a0 = fmaf(bcast(cr, kk), woc[kk], a0);
      a1 = fmaf(bcast(cr, kk + 1), woc[kk + 1], a1);
    }
    float t = a0 + a1 + xin[r * 64 + lane];
    float sum = t;
#pragma unroll
    for (int off = 32; off; off >>= 1) sum += __shfl_xor(sum, off, 64);
    float mean = sum * (1.0f / 64.0f);
    float dv = t - mean;
    float sq = dv * dv;
#pragma unroll
    for (int off = 32; off; off >>= 1) sq += __shfl_xor(sq, off, 64);
    float var = sq * (1.0f / 64.0f);
    float o = dv * rsqrtf(var + EPSV) * gg + bb;
    out1[r * 64 + lane] = o * keep[r];
  }
}

// ---------------------------------------------------------------------------
// Kernel 5: fused FFN: x = LayerNorm(out1 + relu(out1@W1)@W2) * keep.
// R4 proven form: readlane broadcasts in both phases.
// ---------------------------------------------------------------------------
__global__ __launch_bounds__(256) void ffn_fused_kernel(
    const float* __restrict__ out1, const float* __restrict__ w1,
    const float* __restrict__ w2, const float* __restrict__ g,
    const float* __restrict__ bta, const float* __restrict__ keep,
    float* __restrict__ xout) {
  __shared__ float part[4][4][64];   // [row-in-group][wave][lane]
  int tid = threadIdx.x, wave = tid >> 6, lane = tid & 63;
  float w1c[64], w2c[64];
#pragma unroll
  for (int kk = 0; kk < 64; ++kk)
    w1c[kk] = w1[kk * 256 + wave * 64 + lane];     // W1[kk][wave*64+lane]
#pragma unroll
  for (int j = 0; j < 64; ++j)
    w2c[j] = w2[(wave * 64 + j) * 64 + lane];      // W2[wave*64+j][lane]
  float gg = g[lane], bb = bta[lane];
  int row0 = blockIdx.x * 16;
  for (int grp = 0; grp < 4; ++grp) {
    int rbase = row0 + grp * 4;
    float xr0 = out1[(rbase + 0) * 64 + lane];
    float xr1 = out1[(rbase + 1) * 64 + lane];
    float xr2 = out1[(rbase + 2) * 64 + lane];
    float xr3 = out1[(rbase + 3) * 64 + lane];
    float xrs[4] = {xr0, xr1, xr2, xr3};
#pragma unroll
    for (int r = 0; r < 4; ++r) {
      float h0 = 0.f, h1 = 0.f;
#pragma unroll
      for (int kk = 0; kk < 64; kk += 2) {
        h0 = fmaf(bcast(xrs[r], kk), w1c[kk], h0);
        h1 = fmaf(bcast(xrs[r], kk + 1), w1c[kk + 1], h1);
      }
      float hv = fmaxf(h0 + h1, 0.0f);
      float y0 = 0.f, y1 = 0.f;
#pragma unroll
      for (int j = 0; j < 64; j += 2) {
        y0 = fmaf(bcast(hv, j), w2c[j], y0);
        y1 = fmaf(bcast(hv, j + 1), w2c[j + 1], y1);
      }
      part[r][wave][lane] = y0 + y1;
    }
    __syncthreads();
    // wave w finishes row rbase+w (compile-time select, no scratch)
    float xres = (wave == 0) ? xr0 : (wave == 1) ? xr1 : (wave == 2) ? xr2 : xr3;
    float t = part[wave][0][lane] + part[wave][1][lane] +
              part[wave][2][lane] + part[wave][3][lane] + xres;
    float sum = t;
#pragma unroll
    for (int off = 32; off; off >>= 1) sum += __shfl_xor(sum, off, 64);
    float mean = sum * (1.0f / 64.0f);
    float dv = t - mean;
    float sq = dv * dv;
#pragma unroll
    for (int off = 32; off; off >>= 1) sq += __shfl_xor(sq, off, 64);
    float var = sq * (1.0f / 64.0f);
    float o = dv * rsqrtf(var + EPSV) * gg + bb;
    xout[(rbase + wave) * 64 + lane] = o * keep[rbase + wave];
    __syncthreads();   // before next group overwrites part
  }
}

// ---------------------------------------------------------------------------
// Kernel 6: init output: out[b] = out_bias[0]
// ---------------------------------------------------------------------------
__global__ void init_out_kernel(const float* __restrict__ out_bias,
                                float* __restrict__ out) {
  if (threadIdx.x < BB) out[threadIdx.x] = out_bias[0];
}

// ---------------------------------------------------------------------------
// Kernel 7: classifier, weights-in-VGPR + readlane (R4 proven form).
// ---------------------------------------------------------------------------
__global__ __launch_bounds__(256, 3) void classifier_kernel(
    const float* __restrict__ x,
    const float* __restrict__ w1, const float* __restrict__ b1,
    const float* __restrict__ w2, const float* __restrict__ b2,
    const float* __restrict__ w3, const float* __restrict__ b3,
    float* __restrict__ out) {
  int tid = threadIdx.x;
  int lane = tid & 63, wave = tid >> 6;
  float w1c[64], w2c[64];
#pragma unroll
  for (int kk = 0; kk < 64; ++kk) {
    w1c[kk] = w1[kk * 64 + lane];
    w2c[kk] = w2[kk * 64 + lane];
  }
  float w3d = w3[lane];
  float bb1 = b1[lane], bb2 = b2[lane], b3v = b3[0];
  int row0 = blockIdx.x * 32 + wave * 8;
  float wavesum = 0.0f;
  for (int r = row0; r < row0 + 8; ++r) {
    float xr = x[r * 64 + lane];
    float h1a = 0.f, h1b = 0.f;
#pragma unroll
    for (int kk = 0; kk < 64; kk += 2) {
      h1a = fmaf(bcast(xr, kk), w1c[kk], h1a);
      h1b = fmaf(bcast(xr, kk + 1), w1c[kk + 1], h1b);
    }
    float h1 = fmaxf(h1a + h1b + bb1, 0.0f);
    float h2a = 0.f, h2b = 0.f;
#pragma unroll
    for (int kk = 0; kk < 64; kk += 2) {
      h2a = fmaf(bcast(h1, kk), w2c[kk], h2a);
      h2b = fmaf(bcast(h1, kk + 1), w2c[kk + 1], h2b);
    }
    float h2 = fmaxf(h2a + h2b + bb2, 0.0f);
    float p = h2 * w3d;
#pragma unroll
    for (int off = 32; off; off >>= 1) p += __shfl_xor(p, off, 64);
    wavesum += p + b3v;
  }
  if (lane == 0) {
    int b = row0 >> 10;
    atomicAdd(&out[b], wavesum);
  }
}

// ---------------------------------------------------------------------------
extern "C" void kernel_launch(void* const* d_in, const int* in_sizes, int n_in,
                              void* d_out, int out_size, void* d_ws, size_t ws_size,
                              hipStream_t stream) {
  const float* inputs = (const float*)d_in[0];
  const float* emb    = (const float*)d_in[1];
  const float* wq     = (const float*)d_in[2];
  const float* wqb    = (const float*)d_in[3];
  const float* wk     = (const float*)d_in[4];
  const float* wkb    = (const float*)d_in[5];
  const float* wv     = (const float*)d_in[6];
  const float* wvb    = (const float*)d_in[7];
  const float* wo     = (const float*)d_in[8];
  const float* fw1    = (const float*)d_in[9];
  const float* fw2    = (const float*)d_in[10];
  const float* l1g    = (const float*)d_in[11];
  const float* l1b    = (const float*)d_in[12];
  const float* l2g    = (const float*)d_in[13];
  const float* l2b    = (const float*)d_in[14];
  const float* cw1    = (const float*)d_in[15];
  const float* cb1    = (const float*)d_in[16];
  const float* cw2    = (const float*)d_in[17];
  const float* cb2    = (const float*)d_in[18];
  const float* cw3    = (const float*)d_in[19];
  const float* cb3    = (const float*)d_in[20];
  const float* obias  = (const float*)d_in[21];
  float* out = (float*)d_out;

  // Choose split-K factor by available workspace: NK=16 needs ~92 MB,
  // NK=8 (R10 fallback) ~56 MB. ws_size is fixed per harness, so every
  // call takes the same path (graph-capture safe).
  size_t base_floats = (size_t)NROWS * 64 * 5 + NROWS;   // x,q,k,v,out1,keep
  size_t need16 = (base_floats + (size_t)16 * 65536 * 17) * 4;
  int nk = (ws_size >= need16) ? 16 : 8;

  float* ws   = (float*)d_ws;
  float* x    = ws;                           // NROWS*64
  float* keep = x    + (size_t)NROWS * 64;    // NROWS
  float* q    = keep + NROWS;                 // NROWS*64  (B,H,S,DEPTH)
  float* k    = q    + (size_t)NROWS * 64;
  float* v    = k    + (size_t)NROWS * 64;
  float* out1 = v    + (size_t)NROWS * 64;    // NROWS*64
  float* pA   = out1 + (size_t)NROWS * 64;    // nk*65536*16
  float* pL   = pA   + (size_t)nk * 65536 * 16;  // nk*65536

  build_x_kernel<<<4096, 256, 0, stream>>>(inputs, emb, x, keep);

  for (int i = 0; i < 2; ++i) {
    qkv_kernel<<<2048, 64, 0, stream>>>(
        x, wq + i * 4096, wqb + i * 64, wk + i * 4096, wkb + i * 64,
        wv + i * 4096, wvb + i * 64, q, k, v);
    if (nk == 16) {
      attn_partial_kernel<64><<<dim3(128, 16), 256, 0, stream>>>(
          q, k, v, keep, pA, pL);
      wo_ln1_kernel<16><<<1024, 256, 0, stream>>>(
          pA, pL, x, wo + i * 4096, l1g + i * 64, l1b + i * 64, keep, out1);
    } else {
      attn_partial_kernel<128><<<dim3(128, 8), 256, 0, stream>>>(
          q, k, v, keep, pA, pL);
      wo_ln1_kernel<8><<<1024, 256, 0, stream>>>(
          pA, pL, x, wo + i * 4096, l1g + i * 64, l1b + i * 64, keep, out1);
    }
    ffn_fused_kernel<<<1024, 256, 0, stream>>>(
        out1, fw1 + i * 16384, fw2 + i * 16384, l2g + i * 64, l2b + i * 64,
        keep, x);
  }

  init_out_kernel<<<1, 64, 0, stream>>>(obias, out);
  classifier_kernel<<<512, 256, 0, stream>>>(x, cw1, cb1, cw2, cb2, cw3, cb3, out);
}

// Round 15
// 385.499 us; speedup vs baseline: 1.9360x; 1.0669x over previous
//
#include <hip/hip_runtime.h>
#include <hip/hip_bf16.h>
#include <math.h>

// Problem constants (from reference): B=16, S=1024, D=64, H=4, DFF=256, L=2
#define BB 16
#define SS 1024
#define DD 64
#define HH 4
#define DEPTH 16
#define DFF 256
#define NROWS (BB*SS)        // 16384 token rows
#define EPSV 1e-6f
#define NKSPLIT 8            // R14 LESSON: NK=16 is net-negative — combine
                             // traffic (2x partials, +67MB/call) eats the
                             // attn occupancy gain. NK=8 proven best (R10).

typedef float f32x2 __attribute__((ext_vector_type(2)));

// Packed fp32 FMA (one VOP3P instr, 2 MACs). R10: -7% on attn.
// R11: __launch_bounds__ min-waves is a VGPR cap — occupancy via GRID SHAPE.
// R13: keep reduction trip counts compile-time (runtime bounds don't unroll).
__device__ __forceinline__ void pk_fma(f32x2& c, f32x2 a, f32x2 b) {
  asm("v_pk_fma_f32 %0, %1, %2, %0" : "+v"(c) : "v"(a), "v"(b));
}
__device__ __forceinline__ f32x2 lo2(float4 v) { f32x2 r; r.x = v.x; r.y = v.y; return r; }
__device__ __forceinline__ f32x2 hi2(float4 v) { f32x2 r; r.x = v.z; r.y = v.w; return r; }

// Broadcast lane kk via v_readlane. R5/R7: only validated broadcast when
// ~64+ weight VGPRs live. R8: no LDS-dependent branch at loop head.
// R9: manual LDS pipelining neutral.
__device__ __forceinline__ float bcast(float x, int kk) {
  return __int_as_float(__builtin_amdgcn_readlane(__float_as_int(x), kk));
}

// ---------------------------------------------------------------------------
// Kernel 1: build x (B,S,D) and keep (B,S).
// ---------------------------------------------------------------------------
__global__ __launch_bounds__(256) void build_x_kernel(
    const float* __restrict__ inputs, const float* __restrict__ emb,
    float* __restrict__ x, float* __restrict__ keep) {
  int gid = blockIdx.x * 256 + threadIdx.x;   // over NROWS*64 elements
  int row = gid >> 6;
  int d = gid & 63;
  int s = row & (SS - 1);
  float vin = inputs[row];
  bool nan = __builtin_isnan(vin);
  float kp = nan ? 0.0f : 1.0f;
  if (d == 0) keep[row] = kp;
  float val;
  if (d < 63) {
    const float scale = 7.93725393319377f * 8.0f;  // sqrt(63)*sqrt(64)
    val = emb[s * 63 + d] * scale;
  } else {
    val = nan ? 0.0f : vin;
  }
  x[row * 64 + d] = val * kp;
}

// ---------------------------------------------------------------------------
// Kernel 2: QKV projection, weights-in-VGPR + readlane. 4 accumulators per
// output (16-deep chains instead of 32) — these kernels run at 2 waves/SIMD,
// so dep-chain latency is exposed; ILP split halves it. +12 VGPR, no spill
// (~210 < 256 cap). q,k,v layout (B,H,S,DEPTH).
// ---------------------------------------------------------------------------
__global__ __launch_bounds__(64, 2) void qkv_kernel(
    const float* __restrict__ xin,
    const float* __restrict__ wq, const float* __restrict__ wqb,
    const float* __restrict__ wk, const float* __restrict__ wkb,
    const float* __restrict__ wv, const float* __restrict__ wvb,
    float* __restrict__ q, float* __restrict__ k, float* __restrict__ v) {
  int lane = threadIdx.x;
  float wqc[64], wkc[64], wvc[64];
#pragma unroll
  for (int kk = 0; kk < 64; ++kk) {
    wqc[kk] = wq[kk * 64 + lane];
    wkc[kk] = wk[kk * 64 + lane];
    wvc[kk] = wv[kk * 64 + lane];
  }
  float bq = wqb[lane], bk = wkb[lane], bv = wvb[lane];
  int h = lane >> 4, dep = lane & 15;
  int row0 = blockIdx.x * 8;
  for (int r = row0; r < row0 + 8; ++r) {
    float xr = xin[r * 64 + lane];
    float qa0 = 0.f, qa1 = 0.f, qa2 = 0.f, qa3 = 0.f;
    float ka0 = 0.f, ka1 = 0.f, ka2 = 0.f, ka3 = 0.f;
    float va0 = 0.f, va1 = 0.f, va2 = 0.f, va3 = 0.f;
#pragma unroll
    for (int kk = 0; kk < 64; kk += 4) {
      float x0 = bcast(xr, kk);
      float x1 = bcast(xr, kk + 1);
      float x2 = bcast(xr, kk + 2);
      float x3 = bcast(xr, kk + 3);
      qa0 = fmaf(x0, wqc[kk], qa0);     qa1 = fmaf(x1, wqc[kk + 1], qa1);
      qa2 = fmaf(x2, wqc[kk + 2], qa2); qa3 = fmaf(x3, wqc[kk + 3], qa3);
      ka0 = fmaf(x0, wkc[kk], ka0);     ka1 = fmaf(x1, wkc[kk + 1], ka1);
      ka2 = fmaf(x2, wkc[kk + 2], ka2); ka3 = fmaf(x3, wkc[kk + 3], ka3);
      va0 = fmaf(x0, wvc[kk], va0);     va1 = fmaf(x1, wvc[kk + 1], va1);
      va2 = fmaf(x2, wvc[kk + 2], va2); va3 = fmaf(x3, wvc[kk + 3], va3);
    }
    int b = r >> 10, s = r & (SS - 1);
    size_t o = (size_t)(((b * HH + h) * SS + s)) * DEPTH + dep;
    q[o] = (qa0 + qa1) + (qa2 + qa3) + bq;
    k[o] = (ka0 + ka1) + (ka2 + ka3) + bk;
    v[o] = (va0 + va1) + (va2 + va3) + bv;
  }
}

// ---------------------------------------------------------------------------
// Kernel 3: split-K attention partials, 2 queries/thread, K/V chunk in LDS,
// packed-fp32 math (R10 proven form, KCH=128/NK=8). q pre-scaled by 0.25
// (exact pow2). No max-subtraction softmax (exact for this data); partials
// combine by plain addition -> deterministic split-K.
// ---------------------------------------------------------------------------
template <int KCH>
__global__ __launch_bounds__(256, 4) void attn_partial_kernel(
    const float* __restrict__ q, const float* __restrict__ k,
    const float* __restrict__ v, const float* __restrict__ keep,
    float* __restrict__ pA, float* __restrict__ pL) {
  __shared__ __align__(16) float klds[KCH * DEPTH];
  __shared__ __align__(16) float vlds[KCH * DEPTH];
  __shared__ float kplds[KCH];
  int tid = threadIdx.x;
  int p = blockIdx.x * 256 + tid;                // pair id [0, 32768)
  int c = blockIdx.y;                            // key chunk
  int bh = p >> 9;                               // 512 pairs per (b,h)
  int s0 = p & 511;
  int b = bh >> 2;

  const float4* kbase = (const float4*)(k + ((size_t)bh * SS + c * KCH) * DEPTH);
  const float4* vbase = (const float4*)(v + ((size_t)bh * SS + c * KCH) * DEPTH);
#pragma unroll
  for (int i = 0; i < KCH * 4 / 256; ++i) {
    ((float4*)klds)[tid + i * 256] = kbase[tid + i * 256];
    ((float4*)vlds)[tid + i * 256] = vbase[tid + i * 256];
  }
  if (tid < KCH) kplds[tid] = keep[b * SS + c * KCH + tid];
  __syncthreads();

  size_t rowA = (size_t)bh * SS + s0;
  size_t rowB = rowA + 512;
  const float4* qa4 = (const float4*)(q + rowA * DEPTH);
  const float4* qb4 = (const float4*)(q + rowB * DEPTH);
  f32x2 qA[8], qB[8];
#pragma unroll
  for (int i = 0; i < 4; ++i) {
    float4 ta = qa4[i], tb = qb4[i];
    qA[2 * i].x     = ta.x * 0.25f; qA[2 * i].y     = ta.y * 0.25f;
    qA[2 * i + 1].x = ta.z * 0.25f; qA[2 * i + 1].y = ta.w * 0.25f;
    qB[2 * i].x     = tb.x * 0.25f; qB[2 * i].y     = tb.y * 0.25f;
    qB[2 * i + 1].x = tb.z * 0.25f; qB[2 * i + 1].y = tb.w * 0.25f;
  }
  f32x2 z2; z2.x = 0.f; z2.y = 0.f;
  f32x2 aA[8], aB[8];
#pragma unroll
  for (int i = 0; i < 8; ++i) { aA[i] = z2; aB[i] = z2; }
  float lA = 0.0f, lB = 0.0f;
  const float4* kl4 = (const float4*)klds;
  const float4* vl4 = (const float4*)vlds;
  for (int j = 0; j < KCH; ++j) {
    float4 k0 = kl4[j * 4 + 0], k1 = kl4[j * 4 + 1];
    float4 k2 = kl4[j * 4 + 2], k3 = kl4[j * 4 + 3];
    float4 v0 = vl4[j * 4 + 0], v1 = vl4[j * 4 + 1];
    float4 v2 = vl4[j * 4 + 2], v3 = vl4[j * 4 + 3];
    float kpj = kplds[j];
    f32x2 kk0 = lo2(k0), kk1 = hi2(k0), kk2 = lo2(k1), kk3 = hi2(k1);
    f32x2 kk4 = lo2(k2), kk5 = hi2(k2), kk6 = lo2(k3), kk7 = hi2(k3);
    f32x2 dA = z2, dB = z2;
    pk_fma(dA, qA[0], kk0); pk_fma(dB, qB[0], kk0);
    pk_fma(dA, qA[1], kk1); pk_fma(dB, qB[1], kk1);
    pk_fma(dA, qA[2], kk2); pk_fma(dB, qB[2], kk2);
    pk_fma(dA, qA[3], kk3); pk_fma(dB, qB[3], kk3);
    pk_fma(dA, qA[4], kk4); pk_fma(dB, qB[4], kk4);
    pk_fma(dA, qA[5], kk5); pk_fma(dB, qB[5], kk5);
    pk_fma(dA, qA[6], kk6); pk_fma(dB, qB[6], kk6);
    pk_fma(dA, qA[7], kk7); pk_fma(dB, qB[7], kk7);
    float pa = __expf(dA.x + dA.y) * kpj;
    float pb = __expf(dB.x + dB.y) * kpj;
    lA += pa; lB += pb;
    f32x2 pa2, pb2;
    pa2.x = pa; pa2.y = pa; pb2.x = pb; pb2.y = pb;
    f32x2 vv0 = lo2(v0), vv1 = hi2(v0), vv2 = lo2(v1), vv3 = hi2(v1);
    f32x2 vv4 = lo2(v2), vv5 = hi2(v2), vv6 = lo2(v3), vv7 = hi2(v3);
    pk_fma(aA[0], pa2, vv0); pk_fma(aB[0], pb2, vv0);
    pk_fma(aA[1], pa2, vv1); pk_fma(aB[1], pb2, vv1);
    pk_fma(aA[2], pa2, vv2); pk_fma(aB[2], pb2, vv2);
    pk_fma(aA[3], pa2, vv3); pk_fma(aB[3], pb2, vv3);
    pk_fma(aA[4], pa2, vv4); pk_fma(aB[4], pb2, vv4);
    pk_fma(aA[5], pa2, vv5); pk_fma(aB[5], pb2, vv5);
    pk_fma(aA[6], pa2, vv6); pk_fma(aB[6], pb2, vv6);
    pk_fma(aA[7], pa2, vv7); pk_fma(aB[7], pb2, vv7);
  }
  size_t oA = ((size_t)c << 16) + rowA;
  size_t oB = ((size_t)c << 16) + rowB;
  pL[oA] = lA; pL[oB] = lB;
  float4* o4a = (float4*)(pA + oA * 16);
  o4a[0] = make_float4(aA[0].x, aA[0].y, aA[1].x, aA[1].y);
  o4a[1] = make_float4(aA[2].x, aA[2].y, aA[3].x, aA[3].y);
  o4a[2] = make_float4(aA[4].x, aA[4].y, aA[5].x, aA[5].y);
  o4a[3] = make_float4(aA[6].x, aA[6].y, aA[7].x, aA[7].y);
  float4* o4b = (float4*)(pA + oB * 16);
  o4b[0] = make_float4(aB[0].x, aB[0].y, aB[1].x, aB[1].y);
  o4b[1] = make_float4(aB[2].x, aB[2].y, aB[3].x, aB[3].y);
  o4b[2] = make_float4(aB[4].x, aB[4].y, aB[5].x, aB[5].y);
  o4b[3] = make_float4(aB[6].x, aB[6].y, aB[7].x, aB[7].y);
}

// ---------------------------------------------------------------------------
// Kernel 4: out1 = LayerNorm(x + ctx@wo) * keep, fused split-K combine.
// Templated NK (compile-time unroll). 4-chain wo matmul.
// ---------------------------------------------------------------------------
template <int NK>
__global__ __launch_bounds__(256) void wo_ln1_kernel(
    const float* __restrict__ pA, const float* __restrict__ pL,
    const float* __restrict__ xin,
    const float* __restrict__ wo, const float* __restrict__ g,
    const float* __restrict__ bta, const float* __restrict__ keep,
    float* __restrict__ out1) {
  int tid = threadIdx.x;
  int lane = tid & 63;
  float woc[64];
#pragma unroll
  for (int kk = 0; kk < 64; ++kk) woc[kk] = wo[kk * 64 + lane];
  float gg = g[lane], bb = bta[lane];
  int wave = tid >> 6;
  int row0 = blockIdx.x * 16 + wave * 4;
  for (int r = row0; r < row0 + 4; ++r) {
    int b = r >> 10, s = r & (SS - 1);
    int h = lane >> 4, dep = lane & 15;
    size_t rowi = ((size_t)(b * HH + h) << 10) + s;
    float num = 0.0f, den = 0.0f;
#pragma unroll
    for (int c = 0; c < NK; ++c) {
      num += pA[(((size_t)c << 16) + rowi) * 16 + dep];
      den += pL[((size_t)c << 16) + rowi];
    }
    float cr = num * keep[r] / den;   // keep==0 -> exact 0 (den>0 always)
    float a0 = 0.f, a1 = 0.f, a2 = 0.f, a3 = 0.f;
#pragma unroll
    for (int kk = 0; kk < 64; kk += 4) {
      a0 = fmaf(bcast(cr, kk), woc[kk], a0);
      a1 = fmaf(bcast(cr, kk + 1), woc[kk + 1], a1);
      a2 = fmaf(bcast(cr, kk + 2), woc[kk + 2], a2);
      a3 = fmaf(bcast(cr, kk + 3), woc[kk + 3], a3);
    }
    float t = (a0 + a1) + (a2 + a3) + xin[r * 64 + lane];
    float sum = t;
#pragma unroll
    for (int off = 32; off; off >>= 1) sum += __shfl_xor(sum, off, 64);
    float mean = sum * (1.0f / 64.0f);
    float dv = t - mean;
    float sq = dv * dv;
#pragma unroll
    for (int off = 32; off; off >>= 1) sq += __shfl_xor(sq, off, 64);
    float var = sq * (1.0f / 64.0f);
    float o = dv * rsqrtf(var + EPSV) * gg + bb;
    out1[r * 64 + lane] = o * keep[r];
  }
}

// ---------------------------------------------------------------------------
// Kernel 5: fused FFN: x = LayerNorm(out1 + relu(out1@W1)@W2) * keep.
// Readlane broadcasts, 4-chain accumulators in both phases.
// ---------------------------------------------------------------------------
__global__ __launch_bounds__(256) void ffn_fused_kernel(
    const float* __restrict__ out1, const float* __restrict__ w1,
    const float* __restrict__ w2, const float* __restrict__ g,
    const float* __restrict__ bta, const float* __restrict__ keep,
    float* __restrict__ xout) {
  __shared__ float part[4][4][64];   // [row-in-group][wave][lane]
  int tid = threadIdx.x, wave = tid >> 6, lane = tid & 63;
  float w1c[64], w2c[64];
#pragma unroll
  for (int kk = 0; kk < 64; ++kk)
    w1c[kk] = w1[kk * 256 + wave * 64 + lane];     // W1[kk][wave*64+lane]
#pragma unroll
  for (int j = 0; j < 64; ++j)
    w2c[j] = w2[(wave * 64 + j) * 64 + lane];      // W2[wave*64+j][lane]
  float gg = g[lane], bb = bta[lane];
  int row0 = blockIdx.x * 16;
  for (int grp = 0; grp < 4; ++grp) {
    int rbase = row0 + grp * 4;
    float xr0 = out1[(rbase + 0) * 64 + lane];
    float xr1 = out1[(rbase + 1) * 64 + lane];
    float xr2 = out1[(rbase + 2) * 64 + lane];
    float xr3 = out1[(rbase + 3) * 64 + lane];
    float xrs[4] = {xr0, xr1, xr2, xr3};
#pragma unroll
    for (int r = 0; r < 4; ++r) {
      float h0 = 0.f, h1 = 0.f, h2 = 0.f, h3 = 0.f;
#pragma unroll
      for (int kk = 0; kk < 64; kk += 4) {
        h0 = fmaf(bcast(xrs[r], kk), w1c[kk], h0);
        h1 = fmaf(bcast(xrs[r], kk + 1), w1c[kk + 1], h1);
        h2 = fmaf(bcast(xrs[r], kk + 2), w1c[kk + 2], h2);
        h3 = fmaf(bcast(xrs[r], kk + 3), w1c[kk + 3], h3);
      }
      float hv = fmaxf((h0 + h1) + (h2 + h3), 0.0f);
      float y0 = 0.f, y1 = 0.f, y2 = 0.f, y3 = 0.f;
#pragma unroll
      for (int j = 0; j < 64; j += 4) {
        y0 = fmaf(bcast(hv, j), w2c[j], y0);
        y1 = fmaf(bcast(hv, j + 1), w2c[j + 1], y1);
        y2 = fmaf(bcast(hv, j + 2), w2c[j + 2], y2);
        y3 = fmaf(bcast(hv, j + 3), w2c[j + 3], y3);
      }
      part[r][wave][lane] = (y0 + y1) + (y2 + y3);
    }
    __syncthreads();
    // wave w finishes row rbase+w (compile-time select, no scratch)
    float xres = (wave == 0) ? xr0 : (wave == 1) ? xr1 : (wave == 2) ? xr2 : xr3;
    float t = part[wave][0][lane] + part[wave][1][lane] +
              part[wave][2][lane] + part[wave][3][lane] + xres;
    float sum = t;
#pragma unroll
    for (int off = 32; off; off >>= 1) sum += __shfl_xor(sum, off, 64);
    float mean = sum * (1.0f / 64.0f);
    float dv = t - mean;
    float sq = dv * dv;
#pragma unroll
    for (int off = 32; off; off >>= 1) sq += __shfl_xor(sq, off, 64);
    float var = sq * (1.0f / 64.0f);
    float o = dv * rsqrtf(var + EPSV) * gg + bb;
    xout[(rbase + wave) * 64 + lane] = o * keep[rbase + wave];
    __syncthreads();   // before next group overwrites part
  }
}

// ---------------------------------------------------------------------------
// Kernel 6: init output: out[b] = out_bias[0]
// ---------------------------------------------------------------------------
__global__ void init_out_kernel(const float* __restrict__ out_bias,
                                float* __restrict__ out) {
  if (threadIdx.x < BB) out[threadIdx.x] = out_bias[0];
}

// ---------------------------------------------------------------------------
// Kernel 7: classifier, weights-in-VGPR + readlane, 4-chain accumulators.
// ---------------------------------------------------------------------------
__global__ __launch_bounds__(256, 3) void classifier_kernel(
    const float* __restrict__ x,
    const float* __restrict__ w1, const float* __restrict__ b1,
    const float* __restrict__ w2, const float* __restrict__ b2,
    const float* __restrict__ w3, const float* __restrict__ b3,
    float* __restrict__ out) {
  int tid = threadIdx.x;
  int lane = tid & 63, wave = tid >> 6;
  float w1c[64], w2c[64];
#pragma unroll
  for (int kk = 0; kk < 64; ++kk) {
    w1c[kk] = w1[kk * 64 + lane];
    w2c[kk] = w2[kk * 64 + lane];
  }
  float w3d = w3[lane];
  float bb1 = b1[lane], bb2 = b2[lane], b3v = b3[0];
  int row0 = blockIdx.x * 32 + wave * 8;
  float wavesum = 0.0f;
  for (int r = row0; r < row0 + 8; ++r) {
    float xr = x[r * 64 + lane];
    float h1a = 0.f, h1b = 0.f, h1c = 0.f, h1d = 0.f;
#pragma unroll
    for (int kk = 0; kk < 64; kk += 4) {
      h1a = fmaf(bcast(xr, kk), w1c[kk], h1a);
      h1b = fmaf(bcast(xr, kk + 1), w1c[kk + 1], h1b);
      h1c = fmaf(bcast(xr, kk + 2), w1c[kk + 2], h1c);
      h1d = fmaf(bcast(xr, kk + 3), w1c[kk + 3], h1d);
    }
    float h1 = fmaxf((h1a + h1b) + (h1c + h1d) + bb1, 0.0f);
    float h2a = 0.f, h2b = 0.f, h2c = 0.f, h2d = 0.f;
#pragma unroll
    for (int kk = 0; kk < 64; kk += 4) {
      h2a = fmaf(bcast(h1, kk), w2c[kk], h2a);
      h2b = fmaf(bcast(h1, kk + 1), w2c[kk + 1], h2b);
      h2c = fmaf(bcast(h1, kk + 2), w2c[kk + 2], h2c);
      h2d = fmaf(bcast(h1, kk + 3), w2c[kk + 3], h2d);
    }
    float h2 = fmaxf((h2a + h2b) + (h2c + h2d) + bb2, 0.0f);
    float p = h2 * w3d;
#pragma unroll
    for (int off = 32; off; off >>= 1) p += __shfl_xor(p, off, 64);
    wavesum += p + b3v;
  }
  if (lane == 0) {
    int b = row0 >> 10;
    atomicAdd(&out[b], wavesum);
  }
}

// ---------------------------------------------------------------------------
extern "C" void kernel_launch(void* const* d_in, const int* in_sizes, int n_in,
                              void* d_out, int out_size, void* d_ws, size_t ws_size,
                              hipStream_t stream) {
  const float* inputs = (const float*)d_in[0];
  const float* emb    = (const float*)d_in[1];
  const float* wq     = (const float*)d_in[2];
  const float* wqb    = (const float*)d_in[3];
  const float* wk     = (const float*)d_in[4];
  const float* wkb    = (const float*)d_in[5];
  const float* wv     = (const float*)d_in[6];
  const float* wvb    = (const float*)d_in[7];
  const float* wo     = (const float*)d_in[8];
  const float* fw1    = (const float*)d_in[9];
  const float* fw2    = (const float*)d_in[10];
  const float* l1g    = (const float*)d_in[11];
  const float* l1b    = (const float*)d_in[12];
  const float* l2g    = (const float*)d_in[13];
  const float* l2b    = (const float*)d_in[14];
  const float* cw1    = (const float*)d_in[15];
  const float* cb1    = (const float*)d_in[16];
  const float* cw2    = (const float*)d_in[17];
  const float* cb2    = (const float*)d_in[18];
  const float* cw3    = (const float*)d_in[19];
  const float* cb3    = (const float*)d_in[20];
  const float* obias  = (const float*)d_in[21];
  float* out = (float*)d_out;

  // Workspace layout (floats), ~56 MB total (NK=8 partials).
  float* ws   = (float*)d_ws;
  float* x    = ws;                           // NROWS*64
  float* keep = x    + (size_t)NROWS * 64;    // NROWS
  float* q    = keep + NROWS;                 // NROWS*64  (B,H,S,DEPTH)
  float* k    = q    + (size_t)NROWS * 64;
  float* v    = k    + (size_t)NROWS * 64;
  float* out1 = v    + (size_t)NROWS * 64;    // NROWS*64
  float* pA   = out1 + (size_t)NROWS * 64;    // NKSPLIT*65536*16
  float* pL   = pA   + (size_t)NKSPLIT * 65536 * 16;  // NKSPLIT*65536

  build_x_kernel<<<4096, 256, 0, stream>>>(inputs, emb, x, keep);

  for (int i = 0; i < 2; ++i) {
    qkv_kernel<<<2048, 64, 0, stream>>>(
        x, wq + i * 4096, wqb + i * 64, wk + i * 4096, wkb + i * 64,
        wv + i * 4096, wvb + i * 64, q, k, v);
    attn_partial_kernel<128><<<dim3(128, NKSPLIT), 256, 0, stream>>>(
        q, k, v, keep, pA, pL);
    wo_ln1_kernel<NKSPLIT><<<1024, 256, 0, stream>>>(
        pA, pL, x, wo + i * 4096, l1g + i * 64, l1b + i * 64, keep, out1);
    ffn_fused_kernel<<<1024, 256, 0, stream>>>(
        out1, fw1 + i * 16384, fw2 + i * 16384, l2g + i * 64, l2b + i * 64,
        keep, x);
  }

  init_out_kernel<<<1, 64, 0, stream>>>(obias, out);
  classifier_kernel<<<512, 256, 0, stream>>>(x, cw1, cb1, cw2, cb2, cw3, cb3, out);
}

// Round 18
// 384.251 us; speedup vs baseline: 1.9423x; 1.0032x over previous
//
#include <hip/hip_runtime.h>
#include <hip/hip_bf16.h>
#include <math.h>

// Problem constants (from reference): B=16, S=1024, D=64, H=4, DFF=256, L=2
#define BB 16
#define SS 1024
#define DD 64
#define HH 4
#define DEPTH 16
#define DFF 256
#define NROWS (BB*SS)        // 16384 token rows
#define EPSV 1e-6f
#define NKSPLIT 8            // R14: NK=16 net-negative (combine traffic).

typedef float f32x2 __attribute__((ext_vector_type(2)));

// Packed fp32 FMA (one VOP3P instr, 2 MACs). R10: -7% on attn.
// R11: __launch_bounds__ min-waves is a VGPR cap — occupancy via GRID SHAPE.
// R13: keep reduction trip counts compile-time.
// R15: 4-chain ILP in readlane kernels ~ -5us total.
__device__ __forceinline__ void pk_fma(f32x2& c, f32x2 a, f32x2 b) {
  asm("v_pk_fma_f32 %0, %1, %2, %0" : "+v"(c) : "v"(a), "v"(b));
}
__device__ __forceinline__ f32x2 lo2(float4 v) { f32x2 r; r.x = v.x; r.y = v.y; return r; }
__device__ __forceinline__ f32x2 hi2(float4 v) { f32x2 r; r.x = v.z; r.y = v.w; return r; }

// Broadcast lane kk via v_readlane. R5/R7: only validated broadcast when
// ~64+ weight VGPRs live. R8: no LDS-dependent branch at loop head.
__device__ __forceinline__ float bcast(float x, int kk) {
  return __int_as_float(__builtin_amdgcn_readlane(__float_as_int(x), kk));
}

// ---------------------------------------------------------------------------
// Kernel 1: build x (B,S,D) and keep (B,S).
// ---------------------------------------------------------------------------
__global__ __launch_bounds__(256) void build_x_kernel(
    const float* __restrict__ inputs, const float* __restrict__ emb,
    float* __restrict__ x, float* __restrict__ keep) {
  int gid = blockIdx.x * 256 + threadIdx.x;   // over NROWS*64 elements
  int row = gid >> 6;
  int d = gid & 63;
  int s = row & (SS - 1);
  float vin = inputs[row];
  bool nan = __builtin_isnan(vin);
  float kp = nan ? 0.0f : 1.0f;
  if (d == 0) keep[row] = kp;
  float val;
  if (d < 63) {
    const float scale = 7.93725393319377f * 8.0f;  // sqrt(63)*sqrt(64)
    val = emb[s * 63 + d] * scale;
  } else {
    val = nan ? 0.0f : vin;
  }
  x[row * 64 + d] = val * kp;
}

// ---------------------------------------------------------------------------
// Kernel 2: QKV projection, weights-in-VGPR + readlane, 4-chain (R15 form).
// q,k,v layout (B,H,S,DEPTH).
// ---------------------------------------------------------------------------
__global__ __launch_bounds__(64, 2) void qkv_kernel(
    const float* __restrict__ xin,
    const float* __restrict__ wq, const float* __restrict__ wqb,
    const float* __restrict__ wk, const float* __restrict__ wkb,
    const float* __restrict__ wv, const float* __restrict__ wvb,
    float* __restrict__ q, float* __restrict__ k, float* __restrict__ v) {
  int lane = threadIdx.x;
  float wqc[64], wkc[64], wvc[64];
#pragma unroll
  for (int kk = 0; kk < 64; ++kk) {
    wqc[kk] = wq[kk * 64 + lane];
    wkc[kk] = wk[kk * 64 + lane];
    wvc[kk] = wv[kk * 64 + lane];
  }
  float bq = wqb[lane], bk = wkb[lane], bv = wvb[lane];
  int h = lane >> 4, dep = lane & 15;
  int row0 = blockIdx.x * 8;
  for (int r = row0; r < row0 + 8; ++r) {
    float xr = xin[r * 64 + lane];
    float qa0 = 0.f, qa1 = 0.f, qa2 = 0.f, qa3 = 0.f;
    float ka0 = 0.f, ka1 = 0.f, ka2 = 0.f, ka3 = 0.f;
    float va0 = 0.f, va1 = 0.f, va2 = 0.f, va3 = 0.f;
#pragma unroll
    for (int kk = 0; kk < 64; kk += 4) {
      float x0 = bcast(xr, kk);
      float x1 = bcast(xr, kk + 1);
      float x2 = bcast(xr, kk + 2);
      float x3 = bcast(xr, kk + 3);
      qa0 = fmaf(x0, wqc[kk], qa0);     qa1 = fmaf(x1, wqc[kk + 1], qa1);
      qa2 = fmaf(x2, wqc[kk + 2], qa2); qa3 = fmaf(x3, wqc[kk + 3], qa3);
      ka0 = fmaf(x0, wkc[kk], ka0);     ka1 = fmaf(x1, wkc[kk + 1], ka1);
      ka2 = fmaf(x2, wkc[kk + 2], ka2); ka3 = fmaf(x3, wkc[kk + 3], ka3);
      va0 = fmaf(x0, wvc[kk], va0);     va1 = fmaf(x1, wvc[kk + 1], va1);
      va2 = fmaf(x2, wvc[kk + 2], va2); va3 = fmaf(x3, wvc[kk + 3], va3);
    }
    int b = r >> 10, s = r & (SS - 1);
    size_t o = (size_t)(((b * HH + h) * SS + s)) * DEPTH + dep;
    q[o] = (qa0 + qa1) + (qa2 + qa3) + bq;
    k[o] = (ka0 + ka1) + (ka2 + ka3) + bk;
    v[o] = (va0 + va1) + (va2 + va3) + bv;
  }
}

// ---------------------------------------------------------------------------
// Kernel 3: split-K attention partials, 4 QUERIES/THREAD (R4/R6/R7 trend:
// more q/thread beats more waves — 64 pk_fma per 8 LDS reads, 2x R15's
// arithmetic intensity). 16384 threads = 64 blocks x 8 chunks = 512 blocks
// = exactly 2 blocks/CU (no tail). bounds (256,2): VGPR cap 256 >> est.
// ~180 live (R11 lesson: loose cap, occupancy via grid). q pre-scaled by
// 0.25 (exact pow2). No max-subtraction softmax (exact for this data);
// partials combine by plain addition -> deterministic split-K.
// ---------------------------------------------------------------------------
template <int KCH>
__global__ __launch_bounds__(256, 2) void attn_partial_kernel(
    const float* __restrict__ q, const float* __restrict__ k,
    const float* __restrict__ v, const float* __restrict__ keep,
    float* __restrict__ pA, float* __restrict__ pL) {
  __shared__ __align__(16) float klds[KCH * DEPTH];
  __shared__ __align__(16) float vlds[KCH * DEPTH];
  __shared__ float kplds[KCH];
  int tid = threadIdx.x;
  int p = blockIdx.x * 256 + tid;                // quad id [0, 16384)
  int c = blockIdx.y;                            // key chunk
  int bh = p >> 8;                               // 256 quads per (b,h)
  int s0 = p & 255;
  int b = bh >> 2;

  const float4* kbase = (const float4*)(k + ((size_t)bh * SS + c * KCH) * DEPTH);
  const float4* vbase = (const float4*)(v + ((size_t)bh * SS + c * KCH) * DEPTH);
#pragma unroll
  for (int i = 0; i < KCH * 4 / 256; ++i) {
    ((float4*)klds)[tid + i * 256] = kbase[tid + i * 256];
    ((float4*)vlds)[tid + i * 256] = vbase[tid + i * 256];
  }
  if (tid < KCH) kplds[tid] = keep[b * SS + c * KCH + tid];
  __syncthreads();

  size_t row0 = (size_t)bh * SS + s0;
  f32x2 qq[4][8];
#pragma unroll
  for (int qi = 0; qi < 4; ++qi) {
    const float4* q4 = (const float4*)(q + (row0 + 256 * qi) * DEPTH);
#pragma unroll
    for (int i = 0; i < 4; ++i) {
      float4 t = q4[i];
      qq[qi][2 * i].x     = t.x * 0.25f; qq[qi][2 * i].y     = t.y * 0.25f;
      qq[qi][2 * i + 1].x = t.z * 0.25f; qq[qi][2 * i + 1].y = t.w * 0.25f;
    }
  }
  f32x2 z2; z2.x = 0.f; z2.y = 0.f;
  f32x2 acc[4][8];
#pragma unroll
  for (int qi = 0; qi < 4; ++qi)
#pragma unroll
    for (int i = 0; i < 8; ++i) acc[qi][i] = z2;
  float l0 = 0.f, l1 = 0.f, l2 = 0.f, l3 = 0.f;
  const float4* kl4 = (const float4*)klds;
  const float4* vl4 = (const float4*)vlds;
  for (int j = 0; j < KCH; ++j) {
    float4 k0 = kl4[j * 4 + 0], k1 = kl4[j * 4 + 1];
    float4 k2 = kl4[j * 4 + 2], k3 = kl4[j * 4 + 3];
    float4 v0 = vl4[j * 4 + 0], v1 = vl4[j * 4 + 1];
    float4 v2 = vl4[j * 4 + 2], v3 = vl4[j * 4 + 3];
    float kpj = kplds[j];
    f32x2 kk[8];
    kk[0] = lo2(k0); kk[1] = hi2(k0); kk[2] = lo2(k1); kk[3] = hi2(k1);
    kk[4] = lo2(k2); kk[5] = hi2(k2); kk[6] = lo2(k3); kk[7] = hi2(k3);
    f32x2 d0 = z2, d1 = z2, d2 = z2, d3 = z2;
#pragma unroll
    for (int t = 0; t < 8; ++t) {
      pk_fma(d0, qq[0][t], kk[t]);
      pk_fma(d1, qq[1][t], kk[t]);
      pk_fma(d2, qq[2][t], kk[t]);
      pk_fma(d3, qq[3][t], kk[t]);
    }
    float p0 = __expf(d0.x + d0.y) * kpj;
    float p1 = __expf(d1.x + d1.y) * kpj;
    float p2 = __expf(d2.x + d2.y) * kpj;
    float p3 = __expf(d3.x + d3.y) * kpj;
    l0 += p0; l1 += p1; l2 += p2; l3 += p3;
    f32x2 pp0, pp1, pp2, pp3;
    pp0.x = p0; pp0.y = p0; pp1.x = p1; pp1.y = p1;
    pp2.x = p2; pp2.y = p2; pp3.x = p3; pp3.y = p3;
    f32x2 vv[8];
    vv[0] = lo2(v0); vv[1] = hi2(v0); vv[2] = lo2(v1); vv[3] = hi2(v1);
    vv[4] = lo2(v2); vv[5] = hi2(v2); vv[6] = lo2(v3); vv[7] = hi2(v3);
#pragma unroll
    for (int t = 0; t < 8; ++t) {
      pk_fma(acc[0][t], pp0, vv[t]);
      pk_fma(acc[1][t], pp1, vv[t]);
      pk_fma(acc[2][t], pp2, vv[t]);
      pk_fma(acc[3][t], pp3, vv[t]);
    }
  }
  float ls[4] = {l0, l1, l2, l3};
#pragma unroll
  for (int qi = 0; qi < 4; ++qi) {
    size_t orow = ((size_t)c << 16) + row0 + 256 * qi;
    pL[orow] = ls[qi];
    float4* o4 = (float4*)(pA + orow * 16);
    o4[0] = make_float4(acc[qi][0].x, acc[qi][0].y, acc[qi][1].x, acc[qi][1].y);
    o4[1] = make_float4(acc[qi][2].x, acc[qi][2].y, acc[qi][3].x, acc[qi][3].y);
    o4[2] = make_float4(acc[qi][4].x, acc[qi][4].y, acc[qi][5].x, acc[qi][5].y);
    o4[3] = make_float4(acc[qi][6].x, acc[qi][6].y, acc[qi][7].x, acc[qi][7].y);
  }
}

// ---------------------------------------------------------------------------
// Kernel 4: out1 = LayerNorm(x + ctx@wo) * keep, fused split-K combine.
// Templated NK (compile-time unroll). 4-chain wo matmul. (R15 form.)
// ---------------------------------------------------------------------------
template <int NK>
__global__ __launch_bounds__(256) void wo_ln1_kernel(
    const float* __restrict__ pA, const float* __restrict__ pL,
    const float* __restrict__ xin,
    const float* __restrict__ wo, const float* __restrict__ g,
    const float* __restrict__ bta, const float* __restrict__ keep,
    float* __restrict__ out1) {
  int tid = threadIdx.x;
  int lane = tid & 63;
  float woc[64];
#pragma unroll
  for (int kk = 0; kk < 64; ++kk) woc[kk] = wo[kk * 64 + lane];
  float gg = g[lane], bb = bta[lane];
  int wave = tid >> 6;
  int row0 = blockIdx.x * 16 + wave * 4;
  for (int r = row0; r < row0 + 4; ++r) {
    int b = r >> 10, s = r & (SS - 1);
    int h = lane >> 4, dep = lane & 15;
    size_t rowi = ((size_t)(b * HH + h) << 10) + s;
    float num = 0.0f, den = 0.0f;
#pragma unroll
    for (int c = 0; c < NK; ++c) {
      num += pA[(((size_t)c << 16) + rowi) * 16 + dep];
      den += pL[((size_t)c << 16) + rowi];
    }
    float cr = num * keep[r] / den;   // keep==0 -> exact 0 (den>0 always)
    float a0 = 0.f, a1 = 0.f, a2 = 0.f, a3 = 0.f;
#pragma unroll
    for (int kk = 0; kk < 64; kk += 4) {
      a0 = fmaf(bcast(cr, kk), woc[kk], a0);
      a1 = fmaf(bcast(cr, kk + 1), woc[kk + 1], a1);
      a2 = fmaf(bcast(cr, kk + 2), woc[kk + 2], a2);
      a3 = fmaf(bcast(cr, kk + 3), woc[kk + 3], a3);
    }
    float t = (a0 + a1) + (a2 + a3) + xin[r * 64 + lane];
    float sum = t;
#pragma unroll
    for (int off = 32; off; off >>= 1) sum += __shfl_xor(sum, off, 64);
    float mean = sum * (1.0f / 64.0f);
    float dv = t - mean;
    float sq = dv * dv;
#pragma unroll
    for (int off = 32; off; off >>= 1) sq += __shfl_xor(sq, off, 64);
    float var = sq * (1.0f / 64.0f);
    float o = dv * rsqrtf(var + EPSV) * gg + bb;
    out1[r * 64 + lane] = o * keep[r];
  }
}

// ---------------------------------------------------------------------------
// Kernel 5: fused FFN: x = LayerNorm(out1 + relu(out1@W1)@W2) * keep.
// Readlane broadcasts, 4-chain accumulators (R15 form).
// ---------------------------------------------------------------------------
__global__ __launch_bounds__(256) void ffn_fused_kernel(
    const float* __restrict__ out1, const float* __restrict__ w1,
    const float* __restrict__ w2, const float* __restrict__ g,
    const float* __restrict__ bta, const float* __restrict__ keep,
    float* __restrict__ xout) {
  __shared__ float part[4][4][64];   // [row-in-group][wave][lane]
  int tid = threadIdx.x, wave = tid >> 6, lane = tid & 63;
  float w1c[64], w2c[64];
#pragma unroll
  for (int kk = 0; kk < 64; ++kk)
    w1c[kk] = w1[kk * 256 + wave * 64 + lane];     // W1[kk][wave*64+lane]
#pragma unroll
  for (int j = 0; j < 64; ++j)
    w2c[j] = w2[(wave * 64 + j) * 64 + lane];      // W2[wave*64+j][lane]
  float gg = g[lane], bb = bta[lane];
  int row0 = blockIdx.x * 16;
  for (int grp = 0; grp < 4; ++grp) {
    int rbase = row0 + grp * 4;
    float xr0 = out1[(rbase + 0) * 64 + lane];
    float xr1 = out1[(rbase + 1) * 64 + lane];
    float xr2 = out1[(rbase + 2) * 64 + lane];
    float xr3 = out1[(rbase + 3) * 64 + lane];
    float xrs[4] = {xr0, xr1, xr2, xr3};
#pragma unroll
    for (int r = 0; r < 4; ++r) {
      float h0 = 0.f, h1 = 0.f, h2 = 0.f, h3 = 0.f;
#pragma unroll
      for (int kk = 0; kk < 64; kk += 4) {
        h0 = fmaf(bcast(xrs[r], kk), w1c[kk], h0);
        h1 = fmaf(bcast(xrs[r], kk + 1), w1c[kk + 1], h1);
        h2 = fmaf(bcast(xrs[r], kk + 2), w1c[kk + 2], h2);
        h3 = fmaf(bcast(xrs[r], kk + 3), w1c[kk + 3], h3);
      }
      float hv = fmaxf((h0 + h1) + (h2 + h3), 0.0f);
      float y0 = 0.f, y1 = 0.f, y2 = 0.f, y3 = 0.f;
#pragma unroll
      for (int j = 0; j < 64; j += 4) {
        y0 = fmaf(bcast(hv, j), w2c[j], y0);
        y1 = fmaf(bcast(hv, j + 1), w2c[j + 1], y1);
        y2 = fmaf(bcast(hv, j + 2), w2c[j + 2], y2);
        y3 = fmaf(bcast(hv, j + 3), w2c[j + 3], y3);
      }
      part[r][wave][lane] = (y0 + y1) + (y2 + y3);
    }
    __syncthreads();
    // wave w finishes row rbase+w (compile-time select, no scratch)
    float xres = (wave == 0) ? xr0 : (wave == 1) ? xr1 : (wave == 2) ? xr2 : xr3;
    float t = part[wave][0][lane] + part[wave][1][lane] +
              part[wave][2][lane] + part[wave][3][lane] + xres;
    float sum = t;
#pragma unroll
    for (int off = 32; off; off >>= 1) sum += __shfl_xor(sum, off, 64);
    float mean = sum * (1.0f / 64.0f);
    float dv = t - mean;
    float sq = dv * dv;
#pragma unroll
    for (int off = 32; off; off >>= 1) sq += __shfl_xor(sq, off, 64);
    float var = sq * (1.0f / 64.0f);
    float o = dv * rsqrtf(var + EPSV) * gg + bb;
    xout[(rbase + wave) * 64 + lane] = o * keep[rbase + wave];
    __syncthreads();   // before next group overwrites part
  }
}

// ---------------------------------------------------------------------------
// Kernel 6: init output: out[b] = out_bias[0]
// ---------------------------------------------------------------------------
__global__ void init_out_kernel(const float* __restrict__ out_bias,
                                float* __restrict__ out) {
  if (threadIdx.x < BB) out[threadIdx.x] = out_bias[0];
}

// ---------------------------------------------------------------------------
// Kernel 7: classifier, weights-in-VGPR + readlane, 4-chain (R15 form).
// ---------------------------------------------------------------------------
__global__ __launch_bounds__(256, 3) void classifier_kernel(
    const float* __restrict__ x,
    const float* __restrict__ w1, const float* __restrict__ b1,
    const float* __restrict__ w2, const float* __restrict__ b2,
    const float* __restrict__ w3, const float* __restrict__ b3,
    float* __restrict__ out) {
  int tid = threadIdx.x;
  int lane = tid & 63, wave = tid >> 6;
  float w1c[64], w2c[64];
#pragma unroll
  for (int kk = 0; kk < 64; ++kk) {
    w1c[kk] = w1[kk * 64 + lane];
    w2c[kk] = w2[kk * 64 + lane];
  }
  float w3d = w3[lane];
  float bb1 = b1[lane], bb2 = b2[lane], b3v = b3[0];
  int row0 = blockIdx.x * 32 + wave * 8;
  float wavesum = 0.0f;
  for (int r = row0; r < row0 + 8; ++r) {
    float xr = x[r * 64 + lane];
    float h1a = 0.f, h1b = 0.f, h1c = 0.f, h1d = 0.f;
#pragma unroll
    for (int kk = 0; kk < 64; kk += 4) {
      h1a = fmaf(bcast(xr, kk), w1c[kk], h1a);
      h1b = fmaf(bcast(xr, kk + 1), w1c[kk + 1], h1b);
      h1c = fmaf(bcast(xr, kk + 2), w1c[kk + 2], h1c);
      h1d = fmaf(bcast(xr, kk + 3), w1c[kk + 3], h1d);
    }
    float h1 = fmaxf((h1a + h1b) + (h1c + h1d) + bb1, 0.0f);
    float h2a = 0.f, h2b = 0.f, h2c = 0.f, h2d = 0.f;
#pragma unroll
    for (int kk = 0; kk < 64; kk += 4) {
      h2a = fmaf(bcast(h1, kk), w2c[kk], h2a);
      h2b = fmaf(bcast(h1, kk + 1), w2c[kk + 1], h2b);
      h2c = fmaf(bcast(h1, kk + 2), w2c[kk + 2], h2c);
      h2d = fmaf(bcast(h1, kk + 3), w2c[kk + 3], h2d);
    }
    float h2 = fmaxf((h2a + h2b) + (h2c + h2d) + bb2, 0.0f);
    float p = h2 * w3d;
#pragma unroll
    for (int off = 32; off; off >>= 1) p += __shfl_xor(p, off, 64);
    wavesum += p + b3v;
  }
  if (lane == 0) {
    int b = row0 >> 10;
    atomicAdd(&out[b], wavesum);
  }
}

// ---------------------------------------------------------------------------
extern "C" void kernel_launch(void* const* d_in, const int* in_sizes, int n_in,
                              void* d_out, int out_size, void* d_ws, size_t ws_size,
                              hipStream_t stream) {
  const float* inputs = (const float*)d_in[0];
  const float* emb    = (const float*)d_in[1];
  const float* wq     = (const float*)d_in[2];
  const float* wqb    = (const float*)d_in[3];
  const float* wk     = (const float*)d_in[4];
  const float* wkb    = (const float*)d_in[5];
  const float* wv     = (const float*)d_in[6];
  const float* wvb    = (const float*)d_in[7];
  const float* wo     = (const float*)d_in[8];
  const float* fw1    = (const float*)d_in[9];
  const float* fw2    = (const float*)d_in[10];
  const float* l1g    = (const float*)d_in[11];
  const float* l1b    = (const float*)d_in[12];
  const float* l2g    = (const float*)d_in[13];
  const float* l2b    = (const float*)d_in[14];
  const float* cw1    = (const float*)d_in[15];
  const float* cb1    = (const float*)d_in[16];
  const float* cw2    = (const float*)d_in[17];
  const float* cb2    = (const float*)d_in[18];
  const float* cw3    = (const float*)d_in[19];
  const float* cb3    = (const float*)d_in[20];
  const float* obias  = (const float*)d_in[21];
  float* out = (float*)d_out;

  // Workspace layout (floats), ~56 MB total (NK=8 partials).
  float* ws   = (float*)d_ws;
  float* x    = ws;                           // NROWS*64
  float* keep = x    + (size_t)NROWS * 64;    // NROWS
  float* q    = keep + NROWS;                 // NROWS*64  (B,H,S,DEPTH)
  float* k    = q    + (size_t)NROWS * 64;
  float* v    = k    + (size_t)NROWS * 64;
  float* out1 = v    + (size_t)NROWS * 64;    // NROWS*64
  float* pA   = out1 + (size_t)NROWS * 64;    // NKSPLIT*65536*16
  float* pL   = pA   + (size_t)NKSPLIT * 65536 * 16;  // NKSPLIT*65536

  build_x_kernel<<<4096, 256, 0, stream>>>(inputs, emb, x, keep);

  for (int i = 0; i < 2; ++i) {
    qkv_kernel<<<2048, 64, 0, stream>>>(
        x, wq + i * 4096, wqb + i * 64, wk + i * 4096, wkb + i * 64,
        wv + i * 4096, wvb + i * 64, q, k, v);
    attn_partial_kernel<128><<<dim3(64, NKSPLIT), 256, 0, stream>>>(
        q, k, v, keep, pA, pL);
    wo_ln1_kernel<NKSPLIT><<<1024, 256, 0, stream>>>(
        pA, pL, x, wo + i * 4096, l1g + i * 64, l1b + i * 64, keep, out1);
    ffn_fused_kernel<<<1024, 256, 0, stream>>>(
        out1, fw1 + i * 16384, fw2 + i * 16384, l2g + i * 64, l2b + i * 64,
        keep, x);
  }

  init_out_kernel<<<1, 64, 0, stream>>>(obias, out);
  classifier_kernel<<<512, 256, 0, stream>>>(x, cw1, cb1, cw2, cb2, cw3, cb3, out);
}